// Round 14
// baseline (203.432 us; speedup 1.0000x reference)
//
#include <hip/hip_runtime.h>

#define N_NODES 100000
#define N_EDGES 1600000
#define GK 256      // K dim of both GEMMs
#define NBKT 196    // buckets of 512 nodes: (100000+511)>>9
#define NBIN 128    // blocks for bin count/scatter
#define EPB (N_EDGES / NBIN)  // 12500 edges per bin block

typedef __attribute__((ext_vector_type(8))) short bf16x8;
typedef __attribute__((ext_vector_type(4))) float f32x4;
typedef __attribute__((ext_vector_type(2))) float f32x2;
typedef unsigned short ushort_t;

__device__ __forceinline__ float bf2f(unsigned int bits16) {
  union { unsigned int i; float f; } v; v.i = bits16 << 16; return v.f;
}
__device__ __forceinline__ unsigned short f2bf(float f) {
  union { float f; unsigned int i; } v; v.f = f;
  unsigned int u = v.i;
  unsigned int r = (u + 0x7fffu + ((u >> 16) & 1u)) >> 16;  // RNE
  return (unsigned short)r;
}
__device__ __forceinline__ unsigned pkbf(f32x2 a) {
  return (unsigned)f2bf(a[0]) | ((unsigned)f2bf(a[1]) << 16);
}
__device__ __forceinline__ void gload16(const void* g, void* l) {
  __builtin_amdgcn_global_load_lds(
      (const __attribute__((address_space(1))) void*)g,
      (__attribute__((address_space(3))) void*)l, 16, 0, 0);
}

// accumulate one u32 (4 fp8) into acc[b], acc[b+1]  (static indices only)
#define ACC_U32(u, b) \
  acc[b] += __builtin_amdgcn_cvt_pk_f32_fp8((u), false); \
  acc[(b) + 1] += __builtin_amdgcn_cvt_pk_f32_fp8((u), true);
#define ACC_U4(U, b) \
  ACC_U32((U).x, (b)) ACC_U32((U).y, (b) + 2) ACC_U32((U).z, (b) + 4) ACC_U32((U).w, (b) + 6)

// ---------------- fused CSR-count (partial hist) + cvt ----------------
#define CVT_X_WORK (N_NODES * 32)
#define CVT_TOTAL (CVT_X_WORK + 65536 + 32768)
__global__ void count_cvt_kernel(const int* __restrict__ dst, int* __restrict__ partialHist,
                                 const float* __restrict__ x,
                                 const float* __restrict__ W1l, const float* __restrict__ W1r,
                                 const float* __restrict__ W2l, const float* __restrict__ W2r,
                                 ushort_t* __restrict__ axb, unsigned int* __restrict__ xq,
                                 ushort_t* __restrict__ W1bt, ushort_t* __restrict__ W2bt) {
  __shared__ int hist[NBKT];
  int tid = threadIdx.x;
  if (blockIdx.x < NBIN) {
    for (int i = tid; i < NBKT; i += 256) hist[i] = 0;
    __syncthreads();
    const int4* d4 = (const int4*)(dst + blockIdx.x * EPB);
    for (int i = tid; i < EPB / 4; i += 256) {
      int4 v = d4[i];
      atomicAdd(&hist[v.x >> 9], 1); atomicAdd(&hist[v.y >> 9], 1);
      atomicAdd(&hist[v.z >> 9], 1); atomicAdd(&hist[v.w >> 9], 1);
    }
    __syncthreads();
    for (int i = tid; i < NBKT; i += 256) partialHist[i * NBIN + blockIdx.x] = hist[i];
  } else {
    int idx = (blockIdx.x - NBIN) * 256 + tid;
    if (idx < CVT_X_WORK) {
      int n = idx >> 5, j = (idx & 31) << 2;
      float4 v = *(const float4*)(x + (size_t)n * 128 + j);
      ushort4 o;
      o.x = f2bf(v.x); o.y = f2bf(v.y); o.z = f2bf(v.z); o.w = f2bf(v.w);
      *(ushort4*)(axb + (size_t)n * 256 + 128 + j) = o;
      unsigned int q = __builtin_amdgcn_cvt_pk_fp8_f32(v.x, v.y, 0, false);
      q = __builtin_amdgcn_cvt_pk_fp8_f32(v.z, v.w, q, true);
      xq[(size_t)n * 32 + (j >> 2)] = q;
    } else if (idx < CVT_X_WORK + 65536) {
      int t = idx - CVT_X_WORK;
      int n = t >> 8, k = t & 255;
      float v = (k < 128) ? W1l[(size_t)k * 256 + n] : W1r[(size_t)(k - 128) * 256 + n];
      W1bt[t] = f2bf(v);
    } else if (idx < CVT_TOTAL) {
      int t = idx - CVT_X_WORK - 65536;
      int n = t >> 8, k = t & 255;
      float v = (n < 64) ? W2l[(size_t)k * 64 + n] : W2r[(size_t)k * 64 + (n - 64)];
      W2bt[t] = f2bf(v);
    }
  }
}

// sum partials + exclusive scan -> base/cursor (one 256-thread block)
__global__ void scan_buckets_kernel(const int* __restrict__ ph, int* __restrict__ base,
                                    int* __restrict__ cursor, int* __restrict__ rowptr) {
  __shared__ int wsum[4];
  int t = threadIdx.x;
  int v = 0;
  if (t < NBKT) {
    const int* row = ph + t * NBIN;
    for (int b = 0; b < NBIN; ++b) v += row[b];
  }
  int lane = t & 63, wave = t >> 6;
  int s = v;
#pragma unroll
  for (int o = 1; o < 64; o <<= 1) { int u = __shfl_up(s, o); if (lane >= o) s += u; }
  if (lane == 63) wsum[wave] = s;
  __syncthreads();
  if (t == 0) { int c = 0; for (int k = 0; k < 4; ++k) { int u = wsum[k]; wsum[k] = c; c += u; } }
  __syncthreads();
  int excl = s - v + wsum[wave];
  if (t < NBKT) { base[t] = excl; cursor[t] = excl; }
  if (t == 0) { base[NBKT] = N_EDGES; rowptr[N_NODES] = N_EDGES; }
}

// pack = (dst_local<<17) | src
__global__ void bin_scatter_kernel(const int* __restrict__ src, const int* __restrict__ dst,
                                   int* __restrict__ cursor, unsigned int* __restrict__ pairs) {
  __shared__ int hist[NBKT];
  __shared__ int curs[NBKT];
  int tid = threadIdx.x;
  for (int i = tid; i < NBKT; i += 256) hist[i] = 0;
  __syncthreads();
  const int4* d4 = (const int4*)(dst + blockIdx.x * EPB);
  const int4* s4 = (const int4*)(src + blockIdx.x * EPB);
  for (int i = tid; i < EPB / 4; i += 256) {
    int4 v = d4[i];
    atomicAdd(&hist[v.x >> 9], 1); atomicAdd(&hist[v.y >> 9], 1);
    atomicAdd(&hist[v.z >> 9], 1); atomicAdd(&hist[v.w >> 9], 1);
  }
  __syncthreads();
  for (int i = tid; i < NBKT; i += 256) curs[i] = atomicAdd(&cursor[i], hist[i]);
  __syncthreads();
  for (int i = tid; i < EPB / 4; i += 256) {
    int4 v = d4[i];
    int4 u = s4[i];
    int p;
    p = atomicAdd(&curs[v.x >> 9], 1); pairs[p] = ((unsigned)(v.x & 511) << 17) | (unsigned)u.x;
    p = atomicAdd(&curs[v.y >> 9], 1); pairs[p] = ((unsigned)(v.y & 511) << 17) | (unsigned)u.y;
    p = atomicAdd(&curs[v.z >> 9], 1); pairs[p] = ((unsigned)(v.z & 511) << 17) | (unsigned)u.z;
    p = atomicAdd(&curs[v.w >> 9], 1); pairs[p] = ((unsigned)(v.w & 511) << 17) | (unsigned)u.w;
  }
}

__launch_bounds__(256)
__global__ void bucket_csr_kernel(const unsigned int* __restrict__ pairs,
                                  const int* __restrict__ base,
                                  int* __restrict__ rowptr, int* __restrict__ ebuf) {
  __shared__ int hist[512];
  __shared__ int curs[512];
  __shared__ int wsum[4];
  int b = blockIdx.x;
  int tid = threadIdx.x;
  int n0 = b << 9;
  int nn = N_NODES - n0; if (nn > 512) nn = 512;
  int lo = base[b], hi = base[b + 1];
  hist[tid] = 0; hist[tid + 256] = 0;
  __syncthreads();
  for (int i = lo + tid; i < hi; i += 256)
    atomicAdd(&hist[pairs[i] >> 17], 1);
  __syncthreads();
  int h0 = hist[2 * tid], h1 = hist[2 * tid + 1];
  int ps = h0 + h1;
  int lane = tid & 63, wave = tid >> 6;
  int s = ps;
#pragma unroll
  for (int o = 1; o < 64; o <<= 1) { int t = __shfl_up(s, o); if (lane >= o) s += t; }
  if (lane == 63) wsum[wave] = s;
  __syncthreads();
  if (tid == 0) { int c = 0; for (int k = 0; k < 4; ++k) { int t = wsum[k]; wsum[k] = c; c += t; } }
  __syncthreads();
  int base0 = lo + (s - ps) + wsum[wave];
  curs[2 * tid] = base0;
  curs[2 * tid + 1] = base0 + h0;
  if (2 * tid < nn)     rowptr[n0 + 2 * tid] = base0;
  if (2 * tid + 1 < nn) rowptr[n0 + 2 * tid + 1] = base0 + h0;
  __syncthreads();
  for (int i = lo + tid; i < hi; i += 256) {
    unsigned int p = pairs[i];
    int pos = atomicAdd(&curs[p >> 17], 1);
    ebuf[pos] = (int)(p & 0x1FFFF);
  }
}

// ---------------- layer-1 mean aggregation: 16 lanes per node ----------------
// lane q = t&15 owns feats q*8..q*8+7 (4 f32x2 acc = 1 uint2 per edge);
// 4-edge unroll = 4 loads in flight; no cross-lane combine.
__launch_bounds__(256)
__global__ void agg_mean1_kernel(const int* __restrict__ rowptr, const int* __restrict__ ebuf,
                                 const uint2* __restrict__ xq2, ushort_t* __restrict__ axb) {
  int t = blockIdx.x * 256 + threadIdx.x;
  int node = t >> 4, q = t & 15;
  bool valid = node < N_NODES;
  int anode = valid ? node : 0;
  int beg = rowptr[anode], end = rowptr[anode + 1];
  if (!valid) end = beg;
  f32x2 acc[4];
#pragma unroll
  for (int i = 0; i < 4; ++i) acc[i] = (f32x2){0.f, 0.f};
  int e = beg;
  for (; e + 4 <= end; e += 4) {
    int s0 = ebuf[e], s1 = ebuf[e + 1], s2 = ebuf[e + 2], s3 = ebuf[e + 3];
    uint2 a = xq2[(unsigned)(s0 * 16 + q)];
    uint2 b = xq2[(unsigned)(s1 * 16 + q)];
    uint2 c = xq2[(unsigned)(s2 * 16 + q)];
    uint2 d = xq2[(unsigned)(s3 * 16 + q)];
    ACC_U32(a.x, 0) ACC_U32(a.y, 2)
    ACC_U32(b.x, 0) ACC_U32(b.y, 2)
    ACC_U32(c.x, 0) ACC_U32(c.y, 2)
    ACC_U32(d.x, 0) ACC_U32(d.y, 2)
  }
  for (; e < end; ++e) {
    int s = ebuf[e];
    uint2 a = xq2[(unsigned)(s * 16 + q)];
    ACC_U32(a.x, 0) ACC_U32(a.y, 2)
  }
  if (!valid) return;
  float inv = (end > beg) ? 1.0f / (float)(end - beg) : 0.0f;
  f32x2 inv2 = {inv, inv};
#pragma unroll
  for (int i = 0; i < 4; ++i) acc[i] *= inv2;
  uint2 o;
  o.x = pkbf(acc[0]);
  o.y = pkbf(acc[1]);
  uint2 o2;
  o2.x = pkbf(acc[2]);
  o2.y = pkbf(acc[3]);
  uint4 ov = {o.x, o.y, o2.x, o2.y};
  *(uint4*)(axb + (size_t)node * 256 + q * 8) = ov;
}

// ---------------- fused GEMM: h = relu(axb@W1bt^T+b1) kept in LDS; P|Q = h@W2bt^T
// block = 128 rows; two halves of h cols (128 each); gemm2 accumulates across halves.
// ldsH swizzle: 16 slots of 16B per row; slot ^= (row & 15).
__launch_bounds__(256)
__global__ void gemm_fused_kernel(const ushort_t* __restrict__ A,     // axb [M][256]
                                  const ushort_t* __restrict__ W1bt,  // [256][256]
                                  const ushort_t* __restrict__ W2bt,  // [128][256]
                                  const float* __restrict__ b1,
                                  unsigned char* __restrict__ P8, ushort_t* __restrict__ QB,
                                  int M) {
  __shared__ ushort_t ldsA[128 * 64];   // 16 KB
  __shared__ ushort_t ldsB[128 * 64];   // 16 KB
  __shared__ ushort_t ldsH[128 * 128];  // 32 KB
  const int tid = threadIdx.x;
  const int lane = tid & 63;
  const int wm = (tid >> 6) & 1, wn = tid >> 7;
  const int rowBase = blockIdx.x * 128;
  f32x4 acc2[4][4];
#pragma unroll
  for (int i = 0; i < 4; ++i)
#pragma unroll
    for (int j = 0; j < 4; ++j) acc2[i][j] = (f32x4){0.f, 0.f, 0.f, 0.f};

  for (int hp = 0; hp < 2; ++hp) {
    f32x4 acc1[4][4];
#pragma unroll
    for (int i = 0; i < 4; ++i)
#pragma unroll
      for (int j = 0; j < 4; ++j) acc1[i][j] = (f32x4){0.f, 0.f, 0.f, 0.f};
    // ---- gemm1: h[:, hp*128 .. +128] ----
    for (int k0 = 0; k0 < 256; k0 += 64) {
#pragma unroll
      for (int i = 0; i < 4; ++i) {
        int s = tid + i * 256;
        int row = s >> 3, off16 = s & 7;
        int k16 = off16 ^ (row & 7);
        int ga = rowBase + row; if (ga > M - 1) ga = M - 1;
        gload16(A + (size_t)ga * 256 + k0 + k16 * 8, &ldsA[s * 8]);
        gload16(W1bt + (size_t)(hp * 128 + row) * 256 + k0 + k16 * 8, &ldsB[s * 8]);
      }
      __syncthreads();
#pragma unroll
      for (int kc = 0; kc < 2; ++kc) {
        bf16x8 af[4], bg[4];
#pragma unroll
        for (int i = 0; i < 4; ++i) {
          int rA = wm * 64 + i * 16 + (lane & 15);
          int oA = (kc * 4 + (lane >> 4)) ^ (rA & 7);
          af[i] = *(const bf16x8*)&ldsA[rA * 64 + oA * 8];
          int rB = wn * 64 + i * 16 + (lane & 15);
          int oB = (kc * 4 + (lane >> 4)) ^ (rB & 7);
          bg[i] = *(const bf16x8*)&ldsB[rB * 64 + oB * 8];
        }
#pragma unroll
        for (int mi = 0; mi < 4; ++mi)
#pragma unroll
          for (int ni = 0; ni < 4; ++ni)
            acc1[mi][ni] = __builtin_amdgcn_mfma_f32_16x16x32_bf16(af[mi], bg[ni], acc1[mi][ni], 0, 0, 0);
      }
      __syncthreads();
    }
    // ---- bias + relu -> ldsH (swizzled) ----
#pragma unroll
    for (int mi = 0; mi < 4; ++mi) {
#pragma unroll
      for (int r = 0; r < 4; ++r) {
        int row = wm * 64 + mi * 16 + (lane >> 4) * 4 + r;
#pragma unroll
        for (int ni = 0; ni < 4; ++ni) {
          int colh = wn * 64 + ni * 16 + (lane & 15);
          float v = fmaxf(acc1[mi][ni][r] + b1[hp * 128 + colh], 0.f);
          int ss = (colh >> 3) ^ (row & 15);
          ldsH[row * 128 + ss * 8 + (colh & 7)] = f2bf(v);
        }
      }
    }
    __syncthreads();
    // ---- gemm2 partial: K chunk = hp*128 .. +128 ----
    for (int kk = 0; kk < 128; kk += 64) {
#pragma unroll
      for (int i = 0; i < 4; ++i) {
        int s = tid + i * 256;
        int row = s >> 3, off16 = s & 7;
        int k16 = off16 ^ (row & 7);
        gload16(W2bt + (size_t)row * 256 + hp * 128 + kk + k16 * 8, &ldsB[s * 8]);
      }
      __syncthreads();
#pragma unroll
      for (int kc = 0; kc < 2; ++kc) {
        bf16x8 af[4], bg[4];
#pragma unroll
        for (int i = 0; i < 4; ++i) {
          int rA = wm * 64 + i * 16 + (lane & 15);
          int slot = (kk >> 3) + kc * 4 + (lane >> 4);
          int ss = slot ^ (rA & 15);
          af[i] = *(const bf16x8*)&ldsH[rA * 128 + ss * 8];
          int rB = wn * 64 + i * 16 + (lane & 15);
          int oB = (kc * 4 + (lane >> 4)) ^ (rB & 7);
          bg[i] = *(const bf16x8*)&ldsB[rB * 64 + oB * 8];
        }
#pragma unroll
        for (int mi = 0; mi < 4; ++mi)
#pragma unroll
          for (int ni = 0; ni < 4; ++ni)
            acc2[mi][ni] = __builtin_amdgcn_mfma_f32_16x16x32_bf16(af[mi], bg[ni], acc2[mi][ni], 0, 0, 0);
      }
      __syncthreads();
    }
  }
  // ---- epilogue: cols 0..63 -> P8 (fp8), 64..127 -> QB (bf16) ----
#pragma unroll
  for (int mi = 0; mi < 4; ++mi) {
#pragma unroll
    for (int r = 0; r < 4; ++r) {
      int grow = rowBase + wm * 64 + mi * 16 + (lane >> 4) * 4 + r;
      if (grow >= M) continue;
#pragma unroll
      for (int ni = 0; ni < 4; ++ni) {
        float v = acc2[mi][ni][r];
        int c = ni * 16 + (lane & 15);
        if (wn == 0) {
          unsigned int u = __builtin_amdgcn_cvt_pk_fp8_f32(v, v, 0, false);
          P8[(size_t)grow * 64 + c] = (unsigned char)(u & 0xff);
        } else {
          QB[(size_t)grow * 64 + c] = f2bf(v);
        }
      }
    }
  }
}

// ---------------- final: 4 lanes per node, class-partitioned ----------------
__launch_bounds__(256)
__global__ void final_kernel(const int* __restrict__ rowptr, const int* __restrict__ ebuf,
                             const uint4* __restrict__ p84, const ushort_t* __restrict__ qb,
                             const float* __restrict__ b2, float* __restrict__ out) {
  int t = blockIdx.x * 256 + threadIdx.x;
  int node = t >> 2, q = t & 3;
  bool valid = node < N_NODES;
  int anode = valid ? node : 0;
  int beg = rowptr[anode], end = rowptr[anode + 1];
  if (!valid) end = beg;
  f32x2 acc[8];
#pragma unroll
  for (int i = 0; i < 8; ++i) acc[i] = (f32x2){0.f, 0.f};
  int e = beg;
  for (; e + 4 <= end; e += 4) {
    int s0 = ebuf[e], s1 = ebuf[e + 1], s2 = ebuf[e + 2], s3 = ebuf[e + 3];
    uint4 a = p84[(unsigned)(s0 * 4 + q)];
    uint4 b = p84[(unsigned)(s1 * 4 + q)];
    uint4 c = p84[(unsigned)(s2 * 4 + q)];
    uint4 d = p84[(unsigned)(s3 * 4 + q)];
    ACC_U4(a, 0) ACC_U4(b, 0) ACC_U4(c, 0) ACC_U4(d, 0)
  }
  for (; e < end; ++e) {
    int s = ebuf[e];
    uint4 a = p84[(unsigned)(s * 4 + q)];
    ACC_U4(a, 0)
  }
  float inv = (end > beg) ? 1.0f / (float)(end - beg) : 0.0f;
  f32x2 inv2 = {inv, inv};
#pragma unroll
  for (int i = 0; i < 8; ++i) acc[i] *= inv2;
  const uint4* qrow = (const uint4*)(qb + (size_t)anode * 64 + q * 16);
  const float* bb = b2 + q * 16;
#pragma unroll
  for (int k = 0; k < 2; ++k) {
    uint4 qv = qrow[k];
    acc[4 * k + 0][0] += bb[8 * k + 0] + bf2f(qv.x & 0xffff);
    acc[4 * k + 0][1] += bb[8 * k + 1] + bf2f(qv.x >> 16);
    acc[4 * k + 1][0] += bb[8 * k + 2] + bf2f(qv.y & 0xffff);
    acc[4 * k + 1][1] += bb[8 * k + 3] + bf2f(qv.y >> 16);
    acc[4 * k + 2][0] += bb[8 * k + 4] + bf2f(qv.z & 0xffff);
    acc[4 * k + 2][1] += bb[8 * k + 5] + bf2f(qv.z >> 16);
    acc[4 * k + 3][0] += bb[8 * k + 6] + bf2f(qv.w & 0xffff);
    acc[4 * k + 3][1] += bb[8 * k + 7] + bf2f(qv.w >> 16);
  }
  float mx[8];
#pragma unroll
  for (int i = 0; i < 8; ++i) mx[i] = fmaxf(acc[i][0], acc[i][1]);
#pragma unroll
  for (int s = 4; s >= 1; s >>= 1)
#pragma unroll
    for (int j = 0; j < 4; ++j)
      if (j < s) mx[j] = fmaxf(mx[j], mx[j + s]);
  float m = mx[0];
  m = fmaxf(m, __shfl_xor(m, 1));
  m = fmaxf(m, __shfl_xor(m, 2));
  float sm[8];
#pragma unroll
  for (int i = 0; i < 8; ++i)
    sm[i] = __expf(acc[i][0] - m) + __expf(acc[i][1] - m);
#pragma unroll
  for (int s = 4; s >= 1; s >>= 1)
#pragma unroll
    for (int j = 0; j < 4; ++j)
      if (j < s) sm[j] += sm[j + s];
  float ssum = sm[0];
  ssum += __shfl_xor(ssum, 1);
  ssum += __shfl_xor(ssum, 2);
  if (!valid) return;
  float ls = m + __logf(ssum);
  f32x2 ls2 = {ls, ls};
  float4* orow = (float4*)(out + (size_t)node * 64 + q * 16);
#pragma unroll
  for (int i = 0; i < 4; ++i) {
    f32x2 a = acc[2 * i] - ls2;
    f32x2 b = acc[2 * i + 1] - ls2;
    float4 o = {a[0], a[1], b[0], b[1]};
    orow[i] = o;
  }
}

// ---------------- launch ----------------

extern "C" void kernel_launch(void* const* d_in, const int* in_sizes, int n_in,
                              void* d_out, int out_size, void* d_ws, size_t ws_size,
                              hipStream_t stream) {
  const float* x   = (const float*)d_in[0];
  const int*   ei  = (const int*)d_in[1];
  const float* W1l = (const float*)d_in[2];
  const float* b1  = (const float*)d_in[3];
  const float* W1r = (const float*)d_in[4];
  const float* W2l = (const float*)d_in[5];
  const float* b2  = (const float*)d_in[6];
  const float* W2r = (const float*)d_in[7];
  float* out = (float*)d_out;
  const int* src = ei;
  const int* dst = ei + N_EDGES;

  char* w = (char*)d_ws;
  int*      bucketBase  = (int*)(w);                          // 788 B
  int*      bucketCur   = (int*)(w + 1024);                   // 784 B
  int*      partialHist = (int*)(w + 2048);                   // 100.4 KB [NBKT][NBIN]
  int*      rowptr      = (int*)(w + 128ull * 1024);          // 400 KB
  int*      ebuf        = (int*)(w + 1024ull * 1024);         // 6.4 MB (ends 7.4)
  ushort_t* W1bt        = (ushort_t*)(w + 8ull * 1024 * 1024);       // 128 KB
  ushort_t* W2bt        = (ushort_t*)(w + 8ull * 1024 * 1024 + 256 * 1024);  // 64 KB
  ushort_t* axb         = (ushort_t*)(w + 9ull * 1024 * 1024);       // 51.2 MB (ends 60.2)
  unsigned int* pairs   = (unsigned int*)(w + 61ull * 1024 * 1024);  // 6.4 MB
  unsigned int* xq      = (unsigned int*)(w + 113ull * 1024 * 1024); // 12.8 MB fp8 x
  unsigned int* p8      = (unsigned int*)(w + 126ull * 1024 * 1024); // 6.4 MB fp8 P
  ushort_t*     qb      = (ushort_t*)(w + 133ull * 1024 * 1024);     // 12.8 MB bf16 Q

  const int CVT_BLOCKS = (CVT_TOTAL + 255) / 256;
  count_cvt_kernel<<<NBIN + CVT_BLOCKS, 256, 0, stream>>>(
      dst, partialHist, x, W1l, W1r, W2l, W2r, axb, xq, W1bt, W2bt);
  scan_buckets_kernel<<<1, 256, 0, stream>>>(partialHist, bucketBase, bucketCur, rowptr);
  bin_scatter_kernel<<<NBIN, 256, 0, stream>>>(src, dst, bucketCur, pairs);
  bucket_csr_kernel<<<NBKT, 256, 0, stream>>>(pairs, bucketBase, rowptr, ebuf);

  agg_mean1_kernel<<<(16 * N_NODES + 255) / 256, 256, 0, stream>>>(
      rowptr, ebuf, (const uint2*)xq, axb);

  gemm_fused_kernel<<<(N_NODES + 127) / 128, 256, 0, stream>>>(
      axb, W1bt, W2bt, b1, (unsigned char*)p8, qb, N_NODES);

  final_kernel<<<(4 * N_NODES + 255) / 256, 256, 0, stream>>>(
      rowptr, ebuf, (const uint4*)p8, qb, b2, out);
}

// Round 15
// 182.784 us; speedup vs baseline: 1.1130x; 1.1130x over previous
//
#include <hip/hip_runtime.h>

#define N_NODES 100000
#define N_EDGES 1600000
#define GK 256      // K dim of both GEMMs
#define NBKT 196    // buckets of 512 nodes: (100000+511)>>9
#define NBIN 128    // blocks for bin count/scatter
#define EPB (N_EDGES / NBIN)  // 12500 edges per bin block

typedef __attribute__((ext_vector_type(8))) short bf16x8;
typedef __attribute__((ext_vector_type(4))) float f32x4;
typedef __attribute__((ext_vector_type(2))) float f32x2;
typedef unsigned short ushort_t;

__device__ __forceinline__ float bf2f(unsigned int bits16) {
  union { unsigned int i; float f; } v; v.i = bits16 << 16; return v.f;
}
__device__ __forceinline__ unsigned short f2bf(float f) {
  union { float f; unsigned int i; } v; v.f = f;
  unsigned int u = v.i;
  unsigned int r = (u + 0x7fffu + ((u >> 16) & 1u)) >> 16;  // RNE
  return (unsigned short)r;
}
__device__ __forceinline__ unsigned pkbf(f32x2 a) {
  return (unsigned)f2bf(a[0]) | ((unsigned)f2bf(a[1]) << 16);
}
__device__ __forceinline__ void gload16(const void* g, void* l) {
  __builtin_amdgcn_global_load_lds(
      (const __attribute__((address_space(1))) void*)g,
      (__attribute__((address_space(3))) void*)l, 16, 0, 0);
}

// accumulate one u32 (4 fp8) into acc[b], acc[b+1]  (static indices only)
#define ACC_U32(u, b) \
  acc[b] += __builtin_amdgcn_cvt_pk_f32_fp8((u), false); \
  acc[(b) + 1] += __builtin_amdgcn_cvt_pk_f32_fp8((u), true);
#define ACC_U4(U, b) \
  ACC_U32((U).x, (b)) ACC_U32((U).y, (b) + 2) ACC_U32((U).z, (b) + 4) ACC_U32((U).w, (b) + 6)

// ---------------- fused CSR-count (partial hist) + cvt ----------------
#define CVT_X_WORK (N_NODES * 32)
#define CVT_TOTAL (CVT_X_WORK + 65536 + 32768)
__global__ void count_cvt_kernel(const int* __restrict__ dst, int* __restrict__ partialHist,
                                 const float* __restrict__ x,
                                 const float* __restrict__ W1l, const float* __restrict__ W1r,
                                 const float* __restrict__ W2l, const float* __restrict__ W2r,
                                 ushort_t* __restrict__ axb, unsigned int* __restrict__ xq,
                                 ushort_t* __restrict__ W1bt, ushort_t* __restrict__ W2bt) {
  __shared__ int hist[NBKT];
  int tid = threadIdx.x;
  if (blockIdx.x < NBIN) {
    for (int i = tid; i < NBKT; i += 256) hist[i] = 0;
    __syncthreads();
    const int4* d4 = (const int4*)(dst + blockIdx.x * EPB);
    for (int i = tid; i < EPB / 4; i += 256) {
      int4 v = d4[i];
      atomicAdd(&hist[v.x >> 9], 1); atomicAdd(&hist[v.y >> 9], 1);
      atomicAdd(&hist[v.z >> 9], 1); atomicAdd(&hist[v.w >> 9], 1);
    }
    __syncthreads();
    for (int i = tid; i < NBKT; i += 256) partialHist[i * NBIN + blockIdx.x] = hist[i];
  } else {
    int idx = (blockIdx.x - NBIN) * 256 + tid;
    if (idx < CVT_X_WORK) {
      int n = idx >> 5, j = (idx & 31) << 2;
      float4 v = *(const float4*)(x + (size_t)n * 128 + j);
      ushort4 o;
      o.x = f2bf(v.x); o.y = f2bf(v.y); o.z = f2bf(v.z); o.w = f2bf(v.w);
      *(ushort4*)(axb + (size_t)n * 256 + 128 + j) = o;
      unsigned int q = __builtin_amdgcn_cvt_pk_fp8_f32(v.x, v.y, 0, false);
      q = __builtin_amdgcn_cvt_pk_fp8_f32(v.z, v.w, q, true);
      xq[(size_t)n * 32 + (j >> 2)] = q;
    } else if (idx < CVT_X_WORK + 65536) {
      int t = idx - CVT_X_WORK;
      int n = t >> 8, k = t & 255;
      float v = (k < 128) ? W1l[(size_t)k * 256 + n] : W1r[(size_t)(k - 128) * 256 + n];
      W1bt[t] = f2bf(v);
    } else if (idx < CVT_TOTAL) {
      int t = idx - CVT_X_WORK - 65536;
      int n = t >> 8, k = t & 255;
      float v = (n < 64) ? W2l[(size_t)k * 64 + n] : W2r[(size_t)k * 64 + (n - 64)];
      W2bt[t] = f2bf(v);
    }
  }
}

// sum partials + exclusive scan -> base/cursor (one 256-thread block)
__global__ void scan_buckets_kernel(const int* __restrict__ ph, int* __restrict__ base,
                                    int* __restrict__ cursor, int* __restrict__ rowptr) {
  __shared__ int wsum[4];
  int t = threadIdx.x;
  int v = 0;
  if (t < NBKT) {
    const int* row = ph + t * NBIN;
    for (int b = 0; b < NBIN; ++b) v += row[b];
  }
  int lane = t & 63, wave = t >> 6;
  int s = v;
#pragma unroll
  for (int o = 1; o < 64; o <<= 1) { int u = __shfl_up(s, o); if (lane >= o) s += u; }
  if (lane == 63) wsum[wave] = s;
  __syncthreads();
  if (t == 0) { int c = 0; for (int k = 0; k < 4; ++k) { int u = wsum[k]; wsum[k] = c; c += u; } }
  __syncthreads();
  int excl = s - v + wsum[wave];
  if (t < NBKT) { base[t] = excl; cursor[t] = excl; }
  if (t == 0) { base[NBKT] = N_EDGES; rowptr[N_NODES] = N_EDGES; }
}

// pack = (dst_local<<17) | src
__global__ void bin_scatter_kernel(const int* __restrict__ src, const int* __restrict__ dst,
                                   int* __restrict__ cursor, unsigned int* __restrict__ pairs) {
  __shared__ int hist[NBKT];
  __shared__ int curs[NBKT];
  int tid = threadIdx.x;
  for (int i = tid; i < NBKT; i += 256) hist[i] = 0;
  __syncthreads();
  const int4* d4 = (const int4*)(dst + blockIdx.x * EPB);
  const int4* s4 = (const int4*)(src + blockIdx.x * EPB);
  for (int i = tid; i < EPB / 4; i += 256) {
    int4 v = d4[i];
    atomicAdd(&hist[v.x >> 9], 1); atomicAdd(&hist[v.y >> 9], 1);
    atomicAdd(&hist[v.z >> 9], 1); atomicAdd(&hist[v.w >> 9], 1);
  }
  __syncthreads();
  for (int i = tid; i < NBKT; i += 256) curs[i] = atomicAdd(&cursor[i], hist[i]);
  __syncthreads();
  for (int i = tid; i < EPB / 4; i += 256) {
    int4 v = d4[i];
    int4 u = s4[i];
    int p;
    p = atomicAdd(&curs[v.x >> 9], 1); pairs[p] = ((unsigned)(v.x & 511) << 17) | (unsigned)u.x;
    p = atomicAdd(&curs[v.y >> 9], 1); pairs[p] = ((unsigned)(v.y & 511) << 17) | (unsigned)u.y;
    p = atomicAdd(&curs[v.z >> 9], 1); pairs[p] = ((unsigned)(v.z & 511) << 17) | (unsigned)u.z;
    p = atomicAdd(&curs[v.w >> 9], 1); pairs[p] = ((unsigned)(v.w & 511) << 17) | (unsigned)u.w;
  }
}

__launch_bounds__(256)
__global__ void bucket_csr_kernel(const unsigned int* __restrict__ pairs,
                                  const int* __restrict__ base,
                                  int* __restrict__ rowptr, int* __restrict__ ebuf) {
  __shared__ int hist[512];
  __shared__ int curs[512];
  __shared__ int wsum[4];
  int b = blockIdx.x;
  int tid = threadIdx.x;
  int n0 = b << 9;
  int nn = N_NODES - n0; if (nn > 512) nn = 512;
  int lo = base[b], hi = base[b + 1];
  hist[tid] = 0; hist[tid + 256] = 0;
  __syncthreads();
  for (int i = lo + tid; i < hi; i += 256)
    atomicAdd(&hist[pairs[i] >> 17], 1);
  __syncthreads();
  int h0 = hist[2 * tid], h1 = hist[2 * tid + 1];
  int ps = h0 + h1;
  int lane = tid & 63, wave = tid >> 6;
  int s = ps;
#pragma unroll
  for (int o = 1; o < 64; o <<= 1) { int t = __shfl_up(s, o); if (lane >= o) s += t; }
  if (lane == 63) wsum[wave] = s;
  __syncthreads();
  if (tid == 0) { int c = 0; for (int k = 0; k < 4; ++k) { int t = wsum[k]; wsum[k] = c; c += t; } }
  __syncthreads();
  int base0 = lo + (s - ps) + wsum[wave];
  curs[2 * tid] = base0;
  curs[2 * tid + 1] = base0 + h0;
  if (2 * tid < nn)     rowptr[n0 + 2 * tid] = base0;
  if (2 * tid + 1 < nn) rowptr[n0 + 2 * tid + 1] = base0 + h0;
  __syncthreads();
  for (int i = lo + tid; i < hi; i += 256) {
    unsigned int p = pairs[i];
    int pos = atomicAdd(&curs[p >> 17], 1);
    ebuf[pos] = (int)(p & 0x1FFFF);
  }
}

// ---------------- layer-1 mean aggregation: 16 lanes per node ----------------
// lane q = t&15 owns feats q*8..q*8+7 (4 f32x2 acc = 1 uint2 per edge);
// 4-edge unroll = 4 loads in flight; no cross-lane combine.
__launch_bounds__(256)
__global__ void agg_mean1_kernel(const int* __restrict__ rowptr, const int* __restrict__ ebuf,
                                 const uint2* __restrict__ xq2, ushort_t* __restrict__ axb) {
  int t = blockIdx.x * 256 + threadIdx.x;
  int node = t >> 4, q = t & 15;
  bool valid = node < N_NODES;
  int anode = valid ? node : 0;
  int beg = rowptr[anode], end = rowptr[anode + 1];
  if (!valid) end = beg;
  f32x2 acc[4];
#pragma unroll
  for (int i = 0; i < 4; ++i) acc[i] = (f32x2){0.f, 0.f};
  int e = beg;
  for (; e + 4 <= end; e += 4) {
    int s0 = ebuf[e], s1 = ebuf[e + 1], s2 = ebuf[e + 2], s3 = ebuf[e + 3];
    uint2 a = xq2[(unsigned)(s0 * 16 + q)];
    uint2 b = xq2[(unsigned)(s1 * 16 + q)];
    uint2 c = xq2[(unsigned)(s2 * 16 + q)];
    uint2 d = xq2[(unsigned)(s3 * 16 + q)];
    ACC_U32(a.x, 0) ACC_U32(a.y, 2)
    ACC_U32(b.x, 0) ACC_U32(b.y, 2)
    ACC_U32(c.x, 0) ACC_U32(c.y, 2)
    ACC_U32(d.x, 0) ACC_U32(d.y, 2)
  }
  for (; e < end; ++e) {
    int s = ebuf[e];
    uint2 a = xq2[(unsigned)(s * 16 + q)];
    ACC_U32(a.x, 0) ACC_U32(a.y, 2)
  }
  if (!valid) return;
  float inv = (end > beg) ? 1.0f / (float)(end - beg) : 0.0f;
  f32x2 inv2 = {inv, inv};
#pragma unroll
  for (int i = 0; i < 4; ++i) acc[i] *= inv2;
  uint4 ov;
  ov.x = pkbf(acc[0]);
  ov.y = pkbf(acc[1]);
  ov.z = pkbf(acc[2]);
  ov.w = pkbf(acc[3]);
  *(uint4*)(axb + (size_t)node * 256 + q * 8) = ov;
}

// ---------------- bf16 MFMA GEMM (K=256 fixed) ----------------
// MODE 0: C = relu(A@Bt^T + bias) bf16.  MODE 1 (layer2, NC=128):
//   cols 0..63 (wn==0) -> P8 fp8 [N][64];  cols 64..127 (wn==1) -> QB bf16 [N][64]
template<int MODE>
__launch_bounds__(256)
__global__ void gemm_bf16_kernel(const ushort_t* __restrict__ A, const ushort_t* __restrict__ Bt,
                                 const float* __restrict__ bias, ushort_t* __restrict__ C,
                                 unsigned char* __restrict__ P8, ushort_t* __restrict__ QB,
                                 int M, int NC) {
  __shared__ ushort_t ldsA[128 * 64];  // 16 KB
  __shared__ ushort_t ldsB[128 * 64];  // 16 KB
  const int tid = threadIdx.x;
  const int lane = tid & 63;
  const int wm = (tid >> 6) & 1, wn = tid >> 7;
  const int rowBase = blockIdx.x * 128;
  const int colBase = blockIdx.y * 128;
  f32x4 acc[4][4];
#pragma unroll
  for (int i = 0; i < 4; ++i)
#pragma unroll
    for (int j = 0; j < 4; ++j) acc[i][j] = (f32x4){0.f, 0.f, 0.f, 0.f};

  for (int k0 = 0; k0 < GK; k0 += 64) {
#pragma unroll
    for (int i = 0; i < 4; ++i) {
      int s = tid + i * 256;          // 16B slot id
      int row = s >> 3, off16 = s & 7;
      int k16 = off16 ^ (row & 7);    // inverse-swizzled global source
      int ga = rowBase + row; if (ga > M - 1) ga = M - 1;
      gload16(A + (size_t)ga * GK + k0 + k16 * 8, &ldsA[s * 8]);
      gload16(Bt + (size_t)(colBase + row) * GK + k0 + k16 * 8, &ldsB[s * 8]);
    }
    __syncthreads();
#pragma unroll
    for (int kc = 0; kc < 2; ++kc) {
      bf16x8 af[4], bfr[4];
#pragma unroll
      for (int i = 0; i < 4; ++i) {
        int rA = wm * 64 + i * 16 + (lane & 15);
        int oA = (kc * 4 + (lane >> 4)) ^ (rA & 7);   // swizzled read
        af[i] = *(const bf16x8*)&ldsA[rA * 64 + oA * 8];
        int rB = wn * 64 + i * 16 + (lane & 15);
        int oB = (kc * 4 + (lane >> 4)) ^ (rB & 7);
        bfr[i] = *(const bf16x8*)&ldsB[rB * 64 + oB * 8];
      }
#pragma unroll
      for (int mi = 0; mi < 4; ++mi)
#pragma unroll
        for (int ni = 0; ni < 4; ++ni)
          acc[mi][ni] = __builtin_amdgcn_mfma_f32_16x16x32_bf16(af[mi], bfr[ni], acc[mi][ni], 0, 0, 0);
    }
    __syncthreads();
  }
#pragma unroll
  for (int mi = 0; mi < 4; ++mi) {
#pragma unroll
    for (int r = 0; r < 4; ++r) {
      int grow = rowBase + wm * 64 + mi * 16 + (lane >> 4) * 4 + r;
      if (grow >= M) continue;
#pragma unroll
      for (int ni = 0; ni < 4; ++ni) {
        float v = acc[mi][ni][r];
        if (MODE == 0) {
          int gcol = colBase + wn * 64 + ni * 16 + (lane & 15);
          C[(size_t)grow * NC + gcol] = f2bf(fmaxf(v + bias[gcol], 0.f));
        } else {
          int c = ni * 16 + (lane & 15);  // 0..63 within half
          if (wn == 0) {
            unsigned int u = __builtin_amdgcn_cvt_pk_fp8_f32(v, v, 0, false);
            P8[(size_t)grow * 64 + c] = (unsigned char)(u & 0xff);
          } else {
            QB[(size_t)grow * 64 + c] = f2bf(v);
          }
        }
      }
    }
  }
}

// ---------------- final: 4 lanes per node, class-partitioned ----------------
__launch_bounds__(256)
__global__ void final_kernel(const int* __restrict__ rowptr, const int* __restrict__ ebuf,
                             const uint4* __restrict__ p84, const ushort_t* __restrict__ qb,
                             const float* __restrict__ b2, float* __restrict__ out) {
  int t = blockIdx.x * 256 + threadIdx.x;
  int node = t >> 2, q = t & 3;
  bool valid = node < N_NODES;
  int anode = valid ? node : 0;
  int beg = rowptr[anode], end = rowptr[anode + 1];
  if (!valid) end = beg;
  f32x2 acc[8];
#pragma unroll
  for (int i = 0; i < 8; ++i) acc[i] = (f32x2){0.f, 0.f};
  int e = beg;
  for (; e + 4 <= end; e += 4) {
    int s0 = ebuf[e], s1 = ebuf[e + 1], s2 = ebuf[e + 2], s3 = ebuf[e + 3];
    uint4 a = p84[(unsigned)(s0 * 4 + q)];
    uint4 b = p84[(unsigned)(s1 * 4 + q)];
    uint4 c = p84[(unsigned)(s2 * 4 + q)];
    uint4 d = p84[(unsigned)(s3 * 4 + q)];
    ACC_U4(a, 0) ACC_U4(b, 0) ACC_U4(c, 0) ACC_U4(d, 0)
  }
  for (; e < end; ++e) {
    int s = ebuf[e];
    uint4 a = p84[(unsigned)(s * 4 + q)];
    ACC_U4(a, 0)
  }
  float inv = (end > beg) ? 1.0f / (float)(end - beg) : 0.0f;
  f32x2 inv2 = {inv, inv};
#pragma unroll
  for (int i = 0; i < 8; ++i) acc[i] *= inv2;
  const uint4* qrow = (const uint4*)(qb + (size_t)anode * 64 + q * 16);
  const float* bb = b2 + q * 16;
#pragma unroll
  for (int k = 0; k < 2; ++k) {
    uint4 qv = qrow[k];
    acc[4 * k + 0][0] += bb[8 * k + 0] + bf2f(qv.x & 0xffff);
    acc[4 * k + 0][1] += bb[8 * k + 1] + bf2f(qv.x >> 16);
    acc[4 * k + 1][0] += bb[8 * k + 2] + bf2f(qv.y & 0xffff);
    acc[4 * k + 1][1] += bb[8 * k + 3] + bf2f(qv.y >> 16);
    acc[4 * k + 2][0] += bb[8 * k + 4] + bf2f(qv.z & 0xffff);
    acc[4 * k + 2][1] += bb[8 * k + 5] + bf2f(qv.z >> 16);
    acc[4 * k + 3][0] += bb[8 * k + 6] + bf2f(qv.w & 0xffff);
    acc[4 * k + 3][1] += bb[8 * k + 7] + bf2f(qv.w >> 16);
  }
  float mx[8];
#pragma unroll
  for (int i = 0; i < 8; ++i) mx[i] = fmaxf(acc[i][0], acc[i][1]);
#pragma unroll
  for (int s = 4; s >= 1; s >>= 1)
#pragma unroll
    for (int j = 0; j < 4; ++j)
      if (j < s) mx[j] = fmaxf(mx[j], mx[j + s]);
  float m = mx[0];
  m = fmaxf(m, __shfl_xor(m, 1));
  m = fmaxf(m, __shfl_xor(m, 2));
  float sm[8];
#pragma unroll
  for (int i = 0; i < 8; ++i)
    sm[i] = __expf(acc[i][0] - m) + __expf(acc[i][1] - m);
#pragma unroll
  for (int s = 4; s >= 1; s >>= 1)
#pragma unroll
    for (int j = 0; j < 4; ++j)
      if (j < s) sm[j] += sm[j + s];
  float ssum = sm[0];
  ssum += __shfl_xor(ssum, 1);
  ssum += __shfl_xor(ssum, 2);
  if (!valid) return;
  float ls = m + __logf(ssum);
  f32x2 ls2 = {ls, ls};
  float4* orow = (float4*)(out + (size_t)node * 64 + q * 16);
#pragma unroll
  for (int i = 0; i < 4; ++i) {
    f32x2 a = acc[2 * i] - ls2;
    f32x2 b = acc[2 * i + 1] - ls2;
    float4 o = {a[0], a[1], b[0], b[1]};
    orow[i] = o;
  }
}

// ---------------- launch ----------------

extern "C" void kernel_launch(void* const* d_in, const int* in_sizes, int n_in,
                              void* d_out, int out_size, void* d_ws, size_t ws_size,
                              hipStream_t stream) {
  const float* x   = (const float*)d_in[0];
  const int*   ei  = (const int*)d_in[1];
  const float* W1l = (const float*)d_in[2];
  const float* b1  = (const float*)d_in[3];
  const float* W1r = (const float*)d_in[4];
  const float* W2l = (const float*)d_in[5];
  const float* b2  = (const float*)d_in[6];
  const float* W2r = (const float*)d_in[7];
  float* out = (float*)d_out;
  const int* src = ei;
  const int* dst = ei + N_EDGES;

  char* w = (char*)d_ws;
  int*      bucketBase  = (int*)(w);                          // 788 B
  int*      bucketCur   = (int*)(w + 1024);                   // 784 B
  int*      partialHist = (int*)(w + 2048);                   // 100.4 KB [NBKT][NBIN]
  int*      rowptr      = (int*)(w + 128ull * 1024);          // 400 KB
  int*      ebuf        = (int*)(w + 1024ull * 1024);         // 6.4 MB (ends 7.4)
  ushort_t* W1bt        = (ushort_t*)(w + 8ull * 1024 * 1024);       // 128 KB
  ushort_t* W2bt        = (ushort_t*)(w + 8ull * 1024 * 1024 + 256 * 1024);  // 64 KB
  ushort_t* axb         = (ushort_t*)(w + 9ull * 1024 * 1024);       // 51.2 MB (ends 60.2)
  ushort_t* h           = (ushort_t*)(w + 61ull * 1024 * 1024);      // 51.2 MB (ends 112.2)
  unsigned int* pairs   = (unsigned int*)(w + 61ull * 1024 * 1024);  // 6.4 MB, aliases h (dead before gemm1)
  unsigned int* xq      = (unsigned int*)(w + 113ull * 1024 * 1024); // 12.8 MB fp8 x
  unsigned int* p8      = (unsigned int*)(w + 126ull * 1024 * 1024); // 6.4 MB fp8 P
  ushort_t*     qb      = (ushort_t*)(w + 133ull * 1024 * 1024);     // 12.8 MB bf16 Q

  const int CVT_BLOCKS = (CVT_TOTAL + 255) / 256;
  count_cvt_kernel<<<NBIN + CVT_BLOCKS, 256, 0, stream>>>(
      dst, partialHist, x, W1l, W1r, W2l, W2r, axb, xq, W1bt, W2bt);
  scan_buckets_kernel<<<1, 256, 0, stream>>>(partialHist, bucketBase, bucketCur, rowptr);
  bin_scatter_kernel<<<NBIN, 256, 0, stream>>>(src, dst, bucketCur, pairs);
  bucket_csr_kernel<<<NBKT, 256, 0, stream>>>(pairs, bucketBase, rowptr, ebuf);

  agg_mean1_kernel<<<(16 * N_NODES + 255) / 256, 256, 0, stream>>>(
      rowptr, ebuf, (const uint2*)xq, axb);

  gemm_bf16_kernel<0><<<dim3((N_NODES + 127) / 128, 2), 256, 0, stream>>>(
      axb, W1bt, b1, h, nullptr, nullptr, N_NODES, 256);
  gemm_bf16_kernel<1><<<dim3((N_NODES + 127) / 128, 1), 256, 0, stream>>>(
      h, W2bt, nullptr, nullptr, (unsigned char*)p8, qb, N_NODES, 128);

  final_kernel<<<(4 * N_NODES + 255) / 256, 256, 0, stream>>>(
      rowptr, ebuf, (const uint4*)p8, qb, b2, out);
}

// Round 16
// 176.747 us; speedup vs baseline: 1.1510x; 1.0342x over previous
//
#include <hip/hip_runtime.h>

#define N_NODES 100000
#define N_EDGES 1600000
#define GK 256      // K dim of both GEMMs
#define NBKT 196    // buckets of 512 nodes: (100000+511)>>9
#define NBIN 128    // blocks for bin count/scatter
#define EPB (N_EDGES / NBIN)  // 12500 edges per bin block

typedef __attribute__((ext_vector_type(8))) short bf16x8;
typedef __attribute__((ext_vector_type(4))) float f32x4;
typedef __attribute__((ext_vector_type(2))) float f32x2;
typedef unsigned short ushort_t;

__device__ __forceinline__ float bf2f(unsigned int bits16) {
  union { unsigned int i; float f; } v; v.i = bits16 << 16; return v.f;
}
__device__ __forceinline__ unsigned short f2bf(float f) {
  union { float f; unsigned int i; } v; v.f = f;
  unsigned int u = v.i;
  unsigned int r = (u + 0x7fffu + ((u >> 16) & 1u)) >> 16;  // RNE
  return (unsigned short)r;
}
__device__ __forceinline__ unsigned pkbf(f32x2 a) {
  return (unsigned)f2bf(a[0]) | ((unsigned)f2bf(a[1]) << 16);
}
__device__ __forceinline__ unsigned char f2fp8(float v) {
  return (unsigned char)(__builtin_amdgcn_cvt_pk_fp8_f32(v, v, 0, false) & 0xff);
}
__device__ __forceinline__ void gload16(const void* g, void* l) {
  __builtin_amdgcn_global_load_lds(
      (const __attribute__((address_space(1))) void*)g,
      (__attribute__((address_space(3))) void*)l, 16, 0, 0);
}

// accumulate one u32 (4 fp8) into acc[b], acc[b+1]  (static indices only)
#define ACC_U32(u, b) \
  acc[b] += __builtin_amdgcn_cvt_pk_f32_fp8((u), false); \
  acc[(b) + 1] += __builtin_amdgcn_cvt_pk_f32_fp8((u), true);
#define ACC_U4(U, b) \
  ACC_U32((U).x, (b)) ACC_U32((U).y, (b) + 2) ACC_U32((U).z, (b) + 4) ACC_U32((U).w, (b) + 6)

// ---------------- fused CSR-count (partial hist) + cvt ----------------
#define CVT_X_WORK (N_NODES * 32)
#define CVT_TOTAL (CVT_X_WORK + 65536 + 32768)
__global__ void count_cvt_kernel(const int* __restrict__ dst, int* __restrict__ partialHist,
                                 const float* __restrict__ x,
                                 const float* __restrict__ W1l, const float* __restrict__ W1r,
                                 const float* __restrict__ W2l, const float* __restrict__ W2r,
                                 ushort_t* __restrict__ axb, unsigned int* __restrict__ xq,
                                 ushort_t* __restrict__ W1bt, unsigned char* __restrict__ W2bt8) {
  __shared__ int hist[NBKT];
  int tid = threadIdx.x;
  if (blockIdx.x < NBIN) {
    for (int i = tid; i < NBKT; i += 256) hist[i] = 0;
    __syncthreads();
    const int4* d4 = (const int4*)(dst + blockIdx.x * EPB);
    for (int i = tid; i < EPB / 4; i += 256) {
      int4 v = d4[i];
      atomicAdd(&hist[v.x >> 9], 1); atomicAdd(&hist[v.y >> 9], 1);
      atomicAdd(&hist[v.z >> 9], 1); atomicAdd(&hist[v.w >> 9], 1);
    }
    __syncthreads();
    for (int i = tid; i < NBKT; i += 256) partialHist[i * NBIN + blockIdx.x] = hist[i];
  } else {
    int idx = (blockIdx.x - NBIN) * 256 + tid;
    if (idx < CVT_X_WORK) {
      int n = idx >> 5, j = (idx & 31) << 2;
      float4 v = *(const float4*)(x + (size_t)n * 128 + j);
      ushort4 o;
      o.x = f2bf(v.x); o.y = f2bf(v.y); o.z = f2bf(v.z); o.w = f2bf(v.w);
      *(ushort4*)(axb + (size_t)n * 256 + 128 + j) = o;
      unsigned int q = __builtin_amdgcn_cvt_pk_fp8_f32(v.x, v.y, 0, false);
      q = __builtin_amdgcn_cvt_pk_fp8_f32(v.z, v.w, q, true);
      xq[(size_t)n * 32 + (j >> 2)] = q;
    } else if (idx < CVT_X_WORK + 65536) {
      int t = idx - CVT_X_WORK;
      int n = t >> 8, k = t & 255;
      float v = (k < 128) ? W1l[(size_t)k * 256 + n] : W1r[(size_t)(k - 128) * 256 + n];
      W1bt[t] = f2bf(v);
    } else if (idx < CVT_TOTAL) {
      int t = idx - CVT_X_WORK - 65536;
      int n = t >> 8, k = t & 255;
      float v = (n < 64) ? W2l[(size_t)k * 64 + n] : W2r[(size_t)k * 64 + (n - 64)];
      W2bt8[t] = f2fp8(v * 16.0f);   // pre-scaled x16 (fp8 denormal range); /16 in gemm2 epilogue
    }
  }
}

// sum partials + exclusive scan -> base/cursor (one 256-thread block)
__global__ void scan_buckets_kernel(const int* __restrict__ ph, int* __restrict__ base,
                                    int* __restrict__ cursor, int* __restrict__ rowptr) {
  __shared__ int wsum[4];
  int t = threadIdx.x;
  int v = 0;
  if (t < NBKT) {
    const int* row = ph + t * NBIN;
    for (int b = 0; b < NBIN; ++b) v += row[b];
  }
  int lane = t & 63, wave = t >> 6;
  int s = v;
#pragma unroll
  for (int o = 1; o < 64; o <<= 1) { int u = __shfl_up(s, o); if (lane >= o) s += u; }
  if (lane == 63) wsum[wave] = s;
  __syncthreads();
  if (t == 0) { int c = 0; for (int k = 0; k < 4; ++k) { int u = wsum[k]; wsum[k] = c; c += u; } }
  __syncthreads();
  int excl = s - v + wsum[wave];
  if (t < NBKT) { base[t] = excl; cursor[t] = excl; }
  if (t == 0) { base[NBKT] = N_EDGES; rowptr[N_NODES] = N_EDGES; }
}

// pack = (dst_local<<17) | src
__global__ void bin_scatter_kernel(const int* __restrict__ src, const int* __restrict__ dst,
                                   int* __restrict__ cursor, unsigned int* __restrict__ pairs) {
  __shared__ int hist[NBKT];
  __shared__ int curs[NBKT];
  int tid = threadIdx.x;
  for (int i = tid; i < NBKT; i += 256) hist[i] = 0;
  __syncthreads();
  const int4* d4 = (const int4*)(dst + blockIdx.x * EPB);
  const int4* s4 = (const int4*)(src + blockIdx.x * EPB);
  for (int i = tid; i < EPB / 4; i += 256) {
    int4 v = d4[i];
    atomicAdd(&hist[v.x >> 9], 1); atomicAdd(&hist[v.y >> 9], 1);
    atomicAdd(&hist[v.z >> 9], 1); atomicAdd(&hist[v.w >> 9], 1);
  }
  __syncthreads();
  for (int i = tid; i < NBKT; i += 256) curs[i] = atomicAdd(&cursor[i], hist[i]);
  __syncthreads();
  for (int i = tid; i < EPB / 4; i += 256) {
    int4 v = d4[i];
    int4 u = s4[i];
    int p;
    p = atomicAdd(&curs[v.x >> 9], 1); pairs[p] = ((unsigned)(v.x & 511) << 17) | (unsigned)u.x;
    p = atomicAdd(&curs[v.y >> 9], 1); pairs[p] = ((unsigned)(v.y & 511) << 17) | (unsigned)u.y;
    p = atomicAdd(&curs[v.z >> 9], 1); pairs[p] = ((unsigned)(v.z & 511) << 17) | (unsigned)u.z;
    p = atomicAdd(&curs[v.w >> 9], 1); pairs[p] = ((unsigned)(v.w & 511) << 17) | (unsigned)u.w;
  }
}

__launch_bounds__(256)
__global__ void bucket_csr_kernel(const unsigned int* __restrict__ pairs,
                                  const int* __restrict__ base,
                                  int* __restrict__ rowptr, int* __restrict__ ebuf) {
  __shared__ int hist[512];
  __shared__ int curs[512];
  __shared__ int wsum[4];
  int b = blockIdx.x;
  int tid = threadIdx.x;
  int n0 = b << 9;
  int nn = N_NODES - n0; if (nn > 512) nn = 512;
  int lo = base[b], hi = base[b + 1];
  hist[tid] = 0; hist[tid + 256] = 0;
  __syncthreads();
  for (int i = lo + tid; i < hi; i += 256)
    atomicAdd(&hist[pairs[i] >> 17], 1);
  __syncthreads();
  int h0 = hist[2 * tid], h1 = hist[2 * tid + 1];
  int ps = h0 + h1;
  int lane = tid & 63, wave = tid >> 6;
  int s = ps;
#pragma unroll
  for (int o = 1; o < 64; o <<= 1) { int t = __shfl_up(s, o); if (lane >= o) s += t; }
  if (lane == 63) wsum[wave] = s;
  __syncthreads();
  if (tid == 0) { int c = 0; for (int k = 0; k < 4; ++k) { int t = wsum[k]; wsum[k] = c; c += t; } }
  __syncthreads();
  int base0 = lo + (s - ps) + wsum[wave];
  curs[2 * tid] = base0;
  curs[2 * tid + 1] = base0 + h0;
  if (2 * tid < nn)     rowptr[n0 + 2 * tid] = base0;
  if (2 * tid + 1 < nn) rowptr[n0 + 2 * tid + 1] = base0 + h0;
  __syncthreads();
  for (int i = lo + tid; i < hi; i += 256) {
    unsigned int p = pairs[i];
    int pos = atomicAdd(&curs[p >> 17], 1);
    ebuf[pos] = (int)(p & 0x1FFFF);
  }
}

// ---------------- layer-1 mean aggregation: 16 lanes per node ----------------
__launch_bounds__(256)
__global__ void agg_mean1_kernel(const int* __restrict__ rowptr, const int* __restrict__ ebuf,
                                 const uint2* __restrict__ xq2, ushort_t* __restrict__ axb) {
  int t = blockIdx.x * 256 + threadIdx.x;
  int node = t >> 4, q = t & 15;
  bool valid = node < N_NODES;
  int anode = valid ? node : 0;
  int beg = rowptr[anode], end = rowptr[anode + 1];
  if (!valid) end = beg;
  f32x2 acc[4];
#pragma unroll
  for (int i = 0; i < 4; ++i) acc[i] = (f32x2){0.f, 0.f};
  int e = beg;
  for (; e + 4 <= end; e += 4) {
    int s0 = ebuf[e], s1 = ebuf[e + 1], s2 = ebuf[e + 2], s3 = ebuf[e + 3];
    uint2 a = xq2[(unsigned)(s0 * 16 + q)];
    uint2 b = xq2[(unsigned)(s1 * 16 + q)];
    uint2 c = xq2[(unsigned)(s2 * 16 + q)];
    uint2 d = xq2[(unsigned)(s3 * 16 + q)];
    ACC_U32(a.x, 0) ACC_U32(a.y, 2)
    ACC_U32(b.x, 0) ACC_U32(b.y, 2)
    ACC_U32(c.x, 0) ACC_U32(c.y, 2)
    ACC_U32(d.x, 0) ACC_U32(d.y, 2)
  }
  for (; e < end; ++e) {
    int s = ebuf[e];
    uint2 a = xq2[(unsigned)(s * 16 + q)];
    ACC_U32(a.x, 0) ACC_U32(a.y, 2)
  }
  if (!valid) return;
  float inv = (end > beg) ? 1.0f / (float)(end - beg) : 0.0f;
  f32x2 inv2 = {inv, inv};
#pragma unroll
  for (int i = 0; i < 4; ++i) acc[i] *= inv2;
  uint4 ov;
  ov.x = pkbf(acc[0]);
  ov.y = pkbf(acc[1]);
  ov.z = pkbf(acc[2]);
  ov.w = pkbf(acc[3]);
  *(uint4*)(axb + (size_t)node * 256 + q * 8) = ov;
}

// ---------------- gemm1 (bf16 MFMA): h8 = fp8(relu(axb@W1bt^T + b1)) ----------
__launch_bounds__(256)
__global__ void gemm1_kernel(const ushort_t* __restrict__ A, const ushort_t* __restrict__ Bt,
                             const float* __restrict__ bias, unsigned char* __restrict__ H8,
                             int M) {
  __shared__ ushort_t ldsA[128 * 64];  // 16 KB
  __shared__ ushort_t ldsB[128 * 64];  // 16 KB
  const int tid = threadIdx.x;
  const int lane = tid & 63;
  const int wm = (tid >> 6) & 1, wn = tid >> 7;
  const int rowBase = blockIdx.x * 128;
  const int colBase = blockIdx.y * 128;
  f32x4 acc[4][4];
#pragma unroll
  for (int i = 0; i < 4; ++i)
#pragma unroll
    for (int j = 0; j < 4; ++j) acc[i][j] = (f32x4){0.f, 0.f, 0.f, 0.f};

  for (int k0 = 0; k0 < GK; k0 += 64) {
#pragma unroll
    for (int i = 0; i < 4; ++i) {
      int s = tid + i * 256;          // 16B slot id
      int row = s >> 3, off16 = s & 7;
      int k16 = off16 ^ (row & 7);    // inverse-swizzled global source
      int ga = rowBase + row; if (ga > M - 1) ga = M - 1;
      gload16(A + (size_t)ga * GK + k0 + k16 * 8, &ldsA[s * 8]);
      gload16(Bt + (size_t)(colBase + row) * GK + k0 + k16 * 8, &ldsB[s * 8]);
    }
    __syncthreads();
#pragma unroll
    for (int kc = 0; kc < 2; ++kc) {
      bf16x8 af[4], bfr[4];
#pragma unroll
      for (int i = 0; i < 4; ++i) {
        int rA = wm * 64 + i * 16 + (lane & 15);
        int oA = (kc * 4 + (lane >> 4)) ^ (rA & 7);   // swizzled read
        af[i] = *(const bf16x8*)&ldsA[rA * 64 + oA * 8];
        int rB = wn * 64 + i * 16 + (lane & 15);
        int oB = (kc * 4 + (lane >> 4)) ^ (rB & 7);
        bfr[i] = *(const bf16x8*)&ldsB[rB * 64 + oB * 8];
      }
#pragma unroll
      for (int mi = 0; mi < 4; ++mi)
#pragma unroll
        for (int ni = 0; ni < 4; ++ni)
          acc[mi][ni] = __builtin_amdgcn_mfma_f32_16x16x32_bf16(af[mi], bfr[ni], acc[mi][ni], 0, 0, 0);
    }
    __syncthreads();
  }
#pragma unroll
  for (int mi = 0; mi < 4; ++mi) {
#pragma unroll
    for (int r = 0; r < 4; ++r) {
      int grow = rowBase + wm * 64 + mi * 16 + (lane >> 4) * 4 + r;
      if (grow >= M) continue;
#pragma unroll
      for (int ni = 0; ni < 4; ++ni) {
        int gcol = colBase + wn * 64 + ni * 16 + (lane & 15);
        float v = fmaxf(acc[mi][ni][r] + bias[gcol], 0.f);
        H8[(size_t)grow * 256 + gcol] = f2fp8(v);
      }
    }
  }
}

// ---------------- gemm2 (fp8 MFMA): P|Q = (h8 @ W2bt8^T) / 16 ----------------
// tile 128 rows x 128 cols, BK=128 bytes; same 8-slot XOR swizzle as bf16 path.
__launch_bounds__(256)
__global__ void gemm2_fp8_kernel(const unsigned char* __restrict__ A8,
                                 const unsigned char* __restrict__ B8,
                                 unsigned char* __restrict__ P8, ushort_t* __restrict__ QB,
                                 int M) {
  __shared__ unsigned char ldsA[128 * 128];  // 16 KB
  __shared__ unsigned char ldsB[128 * 128];  // 16 KB
  const int tid = threadIdx.x;
  const int lane = tid & 63;
  const int wm = (tid >> 6) & 1, wn = tid >> 7;
  const int rowBase = blockIdx.x * 128;
  f32x4 acc[4][4];
#pragma unroll
  for (int i = 0; i < 4; ++i)
#pragma unroll
    for (int j = 0; j < 4; ++j) acc[i][j] = (f32x4){0.f, 0.f, 0.f, 0.f};

  for (int k0 = 0; k0 < 256; k0 += 128) {
#pragma unroll
    for (int i = 0; i < 4; ++i) {
      int s = tid + i * 256;          // 16B slot id: 128 rows x 8 slots
      int row = s >> 3, off16 = s & 7;
      int k16 = off16 ^ (row & 7);    // inverse-swizzled global source
      int ga = rowBase + row; if (ga > M - 1) ga = M - 1;
      gload16(A8 + (size_t)ga * 256 + k0 + k16 * 16, &ldsA[s * 16]);
      gload16(B8 + (size_t)row * 256 + k0 + k16 * 16, &ldsB[s * 16]);
    }
    __syncthreads();
#pragma unroll
    for (int kc = 0; kc < 4; ++kc) {
      long long af[4], bg[4];
#pragma unroll
      for (int i = 0; i < 4; ++i) {
        int rA = wm * 64 + i * 16 + (lane & 15);
        int kb = kc * 32 + (lane >> 4) * 8;           // byte offset of 8 fp8
        int sA = ((kb >> 4) ^ (rA & 7)) * 16 + (kb & 15);
        af[i] = *(const long long*)&ldsA[rA * 128 + sA];
        int rB = wn * 64 + i * 16 + (lane & 15);
        int sB = ((kb >> 4) ^ (rB & 7)) * 16 + (kb & 15);
        bg[i] = *(const long long*)&ldsB[rB * 128 + sB];
      }
#pragma unroll
      for (int mi = 0; mi < 4; ++mi)
#pragma unroll
        for (int ni = 0; ni < 4; ++ni)
          acc[mi][ni] = __builtin_amdgcn_mfma_f32_16x16x32_fp8_fp8(af[mi], bg[ni], acc[mi][ni], 0, 0, 0);
    }
    __syncthreads();
  }
#pragma unroll
  for (int mi = 0; mi < 4; ++mi) {
#pragma unroll
    for (int r = 0; r < 4; ++r) {
      int grow = rowBase + wm * 64 + mi * 16 + (lane >> 4) * 4 + r;
      if (grow >= M) continue;
#pragma unroll
      for (int ni = 0; ni < 4; ++ni) {
        float v = acc[mi][ni][r] * 0.0625f;   // undo W2 x16 pre-scale
        int c = ni * 16 + (lane & 15);        // 0..63 within half
        if (wn == 0) {
          P8[(size_t)grow * 64 + c] = f2fp8(v);
        } else {
          QB[(size_t)grow * 64 + c] = f2bf(v);
        }
      }
    }
  }
}

// ---------------- final: 4 lanes per node, class-partitioned ----------------
__launch_bounds__(256)
__global__ void final_kernel(const int* __restrict__ rowptr, const int* __restrict__ ebuf,
                             const uint4* __restrict__ p84, const ushort_t* __restrict__ qb,
                             const float* __restrict__ b2, float* __restrict__ out) {
  int t = blockIdx.x * 256 + threadIdx.x;
  int node = t >> 2, q = t & 3;
  bool valid = node < N_NODES;
  int anode = valid ? node : 0;
  int beg = rowptr[anode], end = rowptr[anode + 1];
  if (!valid) end = beg;
  f32x2 acc[8];
#pragma unroll
  for (int i = 0; i < 8; ++i) acc[i] = (f32x2){0.f, 0.f};
  int e = beg;
  for (; e + 4 <= end; e += 4) {
    int s0 = ebuf[e], s1 = ebuf[e + 1], s2 = ebuf[e + 2], s3 = ebuf[e + 3];
    uint4 a = p84[(unsigned)(s0 * 4 + q)];
    uint4 b = p84[(unsigned)(s1 * 4 + q)];
    uint4 c = p84[(unsigned)(s2 * 4 + q)];
    uint4 d = p84[(unsigned)(s3 * 4 + q)];
    ACC_U4(a, 0) ACC_U4(b, 0) ACC_U4(c, 0) ACC_U4(d, 0)
  }
  for (; e < end; ++e) {
    int s = ebuf[e];
    uint4 a = p84[(unsigned)(s * 4 + q)];
    ACC_U4(a, 0)
  }
  float inv = (end > beg) ? 1.0f / (float)(end - beg) : 0.0f;
  f32x2 inv2 = {inv, inv};
#pragma unroll
  for (int i = 0; i < 8; ++i) acc[i] *= inv2;
  const uint4* qrow = (const uint4*)(qb + (size_t)anode * 64 + q * 16);
  const float* bb = b2 + q * 16;
#pragma unroll
  for (int k = 0; k < 2; ++k) {
    uint4 qv = qrow[k];
    acc[4 * k + 0][0] += bb[8 * k + 0] + bf2f(qv.x & 0xffff);
    acc[4 * k + 0][1] += bb[8 * k + 1] + bf2f(qv.x >> 16);
    acc[4 * k + 1][0] += bb[8 * k + 2] + bf2f(qv.y & 0xffff);
    acc[4 * k + 1][1] += bb[8 * k + 3] + bf2f(qv.y >> 16);
    acc[4 * k + 2][0] += bb[8 * k + 4] + bf2f(qv.z & 0xffff);
    acc[4 * k + 2][1] += bb[8 * k + 5] + bf2f(qv.z >> 16);
    acc[4 * k + 3][0] += bb[8 * k + 6] + bf2f(qv.w & 0xffff);
    acc[4 * k + 3][1] += bb[8 * k + 7] + bf2f(qv.w >> 16);
  }
  float mx[8];
#pragma unroll
  for (int i = 0; i < 8; ++i) mx[i] = fmaxf(acc[i][0], acc[i][1]);
#pragma unroll
  for (int s = 4; s >= 1; s >>= 1)
#pragma unroll
    for (int j = 0; j < 4; ++j)
      if (j < s) mx[j] = fmaxf(mx[j], mx[j + s]);
  float m = mx[0];
  m = fmaxf(m, __shfl_xor(m, 1));
  m = fmaxf(m, __shfl_xor(m, 2));
  float sm[8];
#pragma unroll
  for (int i = 0; i < 8; ++i)
    sm[i] = __expf(acc[i][0] - m) + __expf(acc[i][1] - m);
#pragma unroll
  for (int s = 4; s >= 1; s >>= 1)
#pragma unroll
    for (int j = 0; j < 4; ++j)
      if (j < s) sm[j] += sm[j + s];
  float ssum = sm[0];
  ssum += __shfl_xor(ssum, 1);
  ssum += __shfl_xor(ssum, 2);
  if (!valid) return;
  float ls = m + __logf(ssum);
  f32x2 ls2 = {ls, ls};
  float4* orow = (float4*)(out + (size_t)node * 64 + q * 16);
#pragma unroll
  for (int i = 0; i < 4; ++i) {
    f32x2 a = acc[2 * i] - ls2;
    f32x2 b = acc[2 * i + 1] - ls2;
    float4 o = {a[0], a[1], b[0], b[1]};
    orow[i] = o;
  }
}

// ---------------- launch ----------------

extern "C" void kernel_launch(void* const* d_in, const int* in_sizes, int n_in,
                              void* d_out, int out_size, void* d_ws, size_t ws_size,
                              hipStream_t stream) {
  const float* x   = (const float*)d_in[0];
  const int*   ei  = (const int*)d_in[1];
  const float* W1l = (const float*)d_in[2];
  const float* b1  = (const float*)d_in[3];
  const float* W1r = (const float*)d_in[4];
  const float* W2l = (const float*)d_in[5];
  const float* b2  = (const float*)d_in[6];
  const float* W2r = (const float*)d_in[7];
  float* out = (float*)d_out;
  const int* src = ei;
  const int* dst = ei + N_EDGES;

  char* w = (char*)d_ws;
  int*      bucketBase  = (int*)(w);                          // 788 B
  int*      bucketCur   = (int*)(w + 1024);                   // 784 B
  int*      partialHist = (int*)(w + 2048);                   // 100.4 KB [NBKT][NBIN]
  int*      rowptr      = (int*)(w + 128ull * 1024);          // 400 KB
  int*      ebuf        = (int*)(w + 1024ull * 1024);         // 6.4 MB (ends 7.4)
  ushort_t* W1bt        = (ushort_t*)(w + 8ull * 1024 * 1024);          // 128 KB
  unsigned char* W2bt8  = (unsigned char*)(w + 8ull * 1024 * 1024 + 256 * 1024);  // 32 KB
  ushort_t* axb         = (ushort_t*)(w + 9ull * 1024 * 1024);          // 51.2 MB (ends 60.2)
  unsigned char* h8     = (unsigned char*)(w + 61ull * 1024 * 1024);    // 25.6 MB (ends 86.6)
  unsigned int* pairs   = (unsigned int*)(w + 88ull * 1024 * 1024);     // 6.4 MB (ends 94.4)
  unsigned int* xq      = (unsigned int*)(w + 113ull * 1024 * 1024);    // 12.8 MB fp8 x
  unsigned int* p8      = (unsigned int*)(w + 126ull * 1024 * 1024);    // 6.4 MB fp8 P
  ushort_t*     qb      = (ushort_t*)(w + 133ull * 1024 * 1024);        // 12.8 MB bf16 Q

  const int CVT_BLOCKS = (CVT_TOTAL + 255) / 256;
  count_cvt_kernel<<<NBIN + CVT_BLOCKS, 256, 0, stream>>>(
      dst, partialHist, x, W1l, W1r, W2l, W2r, axb, xq, W1bt, W2bt8);
  scan_buckets_kernel<<<1, 256, 0, stream>>>(partialHist, bucketBase, bucketCur, rowptr);
  bin_scatter_kernel<<<NBIN, 256, 0, stream>>>(src, dst, bucketCur, pairs);
  bucket_csr_kernel<<<NBKT, 256, 0, stream>>>(pairs, bucketBase, rowptr, ebuf);

  agg_mean1_kernel<<<(16 * N_NODES + 255) / 256, 256, 0, stream>>>(
      rowptr, ebuf, (const uint2*)xq, axb);

  gemm1_kernel<<<dim3((N_NODES + 127) / 128, 2), 256, 0, stream>>>(
      axb, W1bt, b1, h8, N_NODES);
  gemm2_fp8_kernel<<<(N_NODES + 127) / 128, 256, 0, stream>>>(
      h8, W2bt8, (unsigned char*)p8, qb, N_NODES);

  final_kernel<<<(4 * N_NODES + 255) / 256, 256, 0, stream>>>(
      rowptr, ebuf, (const uint4*)p8, qb, b2, out);
}

// Round 17
// 166.881 us; speedup vs baseline: 1.2190x; 1.0591x over previous
//
#include <hip/hip_runtime.h>

#define N_NODES 100000
#define N_EDGES 1600000
#define NBKT 196    // buckets of 512 nodes
#define NBIN 128    // blocks for bin count/scatter
#define EPB (N_EDGES / NBIN)  // 12500 edges per bin block

typedef __attribute__((ext_vector_type(4))) float f32x4;
typedef __attribute__((ext_vector_type(2))) float f32x2;
typedef unsigned short ushort_t;

__device__ __forceinline__ float bf2f(unsigned int bits16) {
  union { unsigned int i; float f; } v; v.i = bits16 << 16; return v.f;
}
__device__ __forceinline__ unsigned short f2bf(float f) {
  union { float f; unsigned int i; } v; v.f = f;
  unsigned int u = v.i;
  unsigned int r = (u + 0x7fffu + ((u >> 16) & 1u)) >> 16;  // RNE
  return (unsigned short)r;
}
__device__ __forceinline__ unsigned char f2fp8(float v) {
  return (unsigned char)(__builtin_amdgcn_cvt_pk_fp8_f32(v, v, 0, false) & 0xff);
}
__device__ __forceinline__ void gload16(const void* g, void* l) {
  __builtin_amdgcn_global_load_lds(
      (const __attribute__((address_space(1))) void*)g,
      (__attribute__((address_space(3))) void*)l, 16, 0, 0);
}

// accumulate one u32 (4 fp8) into acc[b], acc[b+1]  (static indices only)
#define ACC_U32(u, b) \
  acc[b] += __builtin_amdgcn_cvt_pk_f32_fp8((u), false); \
  acc[(b) + 1] += __builtin_amdgcn_cvt_pk_f32_fp8((u), true);
#define ACC_U4(U, b) \
  ACC_U32((U).x, (b)) ACC_U32((U).y, (b) + 2) ACC_U32((U).z, (b) + 4) ACC_U32((U).w, (b) + 6)

// ---------------- fused CSR-count (partial hist) + cvt ----------------
// a8: [N][256] fp8 (cols 0..127 mean1 by agg, 128..255 x);  xq: [N][128] fp8
#define CVT_X_WORK (N_NODES * 32)
#define CVT_TOTAL (CVT_X_WORK + 65536 + 32768)
__global__ void count_cvt_kernel(const int* __restrict__ dst, int* __restrict__ partialHist,
                                 const float* __restrict__ x,
                                 const float* __restrict__ W1l, const float* __restrict__ W1r,
                                 const float* __restrict__ W2l, const float* __restrict__ W2r,
                                 unsigned char* __restrict__ a8, unsigned int* __restrict__ xq,
                                 unsigned char* __restrict__ W1bt8, unsigned char* __restrict__ W2bt8) {
  __shared__ int hist[NBKT];
  int tid = threadIdx.x;
  if (blockIdx.x < NBIN) {
    for (int i = tid; i < NBKT; i += 256) hist[i] = 0;
    __syncthreads();
    const int4* d4 = (const int4*)(dst + blockIdx.x * EPB);
    for (int i = tid; i < EPB / 4; i += 256) {
      int4 v = d4[i];
      atomicAdd(&hist[v.x >> 9], 1); atomicAdd(&hist[v.y >> 9], 1);
      atomicAdd(&hist[v.z >> 9], 1); atomicAdd(&hist[v.w >> 9], 1);
    }
    __syncthreads();
    for (int i = tid; i < NBKT; i += 256) partialHist[i * NBIN + blockIdx.x] = hist[i];
  } else {
    int idx = (blockIdx.x - NBIN) * 256 + tid;
    if (idx < CVT_X_WORK) {
      int n = idx >> 5, j = (idx & 31) << 2;
      float4 v = *(const float4*)(x + (size_t)n * 128 + j);
      unsigned int q = __builtin_amdgcn_cvt_pk_fp8_f32(v.x, v.y, 0, false);
      q = __builtin_amdgcn_cvt_pk_fp8_f32(v.z, v.w, q, true);
      xq[(size_t)n * 32 + (j >> 2)] = q;
      *(unsigned int*)(a8 + (size_t)n * 256 + 128 + j) = q;   // x-part of A
    } else if (idx < CVT_X_WORK + 65536) {
      int t = idx - CVT_X_WORK;
      int n = t >> 8, k = t & 255;
      float v = (k < 128) ? W1l[(size_t)k * 256 + n] : W1r[(size_t)(k - 128) * 256 + n];
      W1bt8[t] = f2fp8(v * 16.0f);   // x16 pre-scale; /16 in gemm1 epilogue
    } else if (idx < CVT_TOTAL) {
      int t = idx - CVT_X_WORK - 65536;
      int n = t >> 8, k = t & 255;
      float v = (n < 64) ? W2l[(size_t)k * 64 + n] : W2r[(size_t)k * 64 + (n - 64)];
      W2bt8[t] = f2fp8(v * 16.0f);
    }
  }
}

// sum partials + exclusive scan -> base/cursor
__global__ void scan_buckets_kernel(const int* __restrict__ ph, int* __restrict__ base,
                                    int* __restrict__ cursor, int* __restrict__ rowptr) {
  __shared__ int wsum[4];
  int t = threadIdx.x;
  int v = 0;
  if (t < NBKT) {
    const int* row = ph + t * NBIN;
    for (int b = 0; b < NBIN; ++b) v += row[b];
  }
  int lane = t & 63, wave = t >> 6;
  int s = v;
#pragma unroll
  for (int o = 1; o < 64; o <<= 1) { int u = __shfl_up(s, o); if (lane >= o) s += u; }
  if (lane == 63) wsum[wave] = s;
  __syncthreads();
  if (t == 0) { int c = 0; for (int k = 0; k < 4; ++k) { int u = wsum[k]; wsum[k] = c; c += u; } }
  __syncthreads();
  int excl = s - v + wsum[wave];
  if (t < NBKT) { base[t] = excl; cursor[t] = excl; }
  if (t == 0) { base[NBKT] = N_EDGES; rowptr[N_NODES] = N_EDGES; }
}

// pack = (dst_local<<17) | src
__global__ void bin_scatter_kernel(const int* __restrict__ src, const int* __restrict__ dst,
                                   int* __restrict__ cursor, unsigned int* __restrict__ pairs) {
  __shared__ int hist[NBKT];
  __shared__ int curs[NBKT];
  int tid = threadIdx.x;
  for (int i = tid; i < NBKT; i += 256) hist[i] = 0;
  __syncthreads();
  const int4* d4 = (const int4*)(dst + blockIdx.x * EPB);
  const int4* s4 = (const int4*)(src + blockIdx.x * EPB);
  for (int i = tid; i < EPB / 4; i += 256) {
    int4 v = d4[i];
    atomicAdd(&hist[v.x >> 9], 1); atomicAdd(&hist[v.y >> 9], 1);
    atomicAdd(&hist[v.z >> 9], 1); atomicAdd(&hist[v.w >> 9], 1);
  }
  __syncthreads();
  for (int i = tid; i < NBKT; i += 256) curs[i] = atomicAdd(&cursor[i], hist[i]);
  __syncthreads();
  for (int i = tid; i < EPB / 4; i += 256) {
    int4 v = d4[i];
    int4 u = s4[i];
    int p;
    p = atomicAdd(&curs[v.x >> 9], 1); pairs[p] = ((unsigned)(v.x & 511) << 17) | (unsigned)u.x;
    p = atomicAdd(&curs[v.y >> 9], 1); pairs[p] = ((unsigned)(v.y & 511) << 17) | (unsigned)u.y;
    p = atomicAdd(&curs[v.z >> 9], 1); pairs[p] = ((unsigned)(v.z & 511) << 17) | (unsigned)u.z;
    p = atomicAdd(&curs[v.w >> 9], 1); pairs[p] = ((unsigned)(v.w & 511) << 17) | (unsigned)u.w;
  }
}

__launch_bounds__(256)
__global__ void bucket_csr_kernel(const unsigned int* __restrict__ pairs,
                                  const int* __restrict__ base,
                                  int* __restrict__ rowptr, int* __restrict__ ebuf) {
  __shared__ int hist[512];
  __shared__ int curs[512];
  __shared__ int wsum[4];
  int b = blockIdx.x;
  int tid = threadIdx.x;
  int n0 = b << 9;
  int nn = N_NODES - n0; if (nn > 512) nn = 512;
  int lo = base[b], hi = base[b + 1];
  hist[tid] = 0; hist[tid + 256] = 0;
  __syncthreads();
  for (int i = lo + tid; i < hi; i += 256)
    atomicAdd(&hist[pairs[i] >> 17], 1);
  __syncthreads();
  int h0 = hist[2 * tid], h1 = hist[2 * tid + 1];
  int ps = h0 + h1;
  int lane = tid & 63, wave = tid >> 6;
  int s = ps;
#pragma unroll
  for (int o = 1; o < 64; o <<= 1) { int t = __shfl_up(s, o); if (lane >= o) s += t; }
  if (lane == 63) wsum[wave] = s;
  __syncthreads();
  if (tid == 0) { int c = 0; for (int k = 0; k < 4; ++k) { int t = wsum[k]; wsum[k] = c; c += t; } }
  __syncthreads();
  int base0 = lo + (s - ps) + wsum[wave];
  curs[2 * tid] = base0;
  curs[2 * tid + 1] = base0 + h0;
  if (2 * tid < nn)     rowptr[n0 + 2 * tid] = base0;
  if (2 * tid + 1 < nn) rowptr[n0 + 2 * tid + 1] = base0 + h0;
  __syncthreads();
  for (int i = lo + tid; i < hi; i += 256) {
    unsigned int p = pairs[i];
    int pos = atomicAdd(&curs[p >> 17], 1);
    ebuf[pos] = (int)(p & 0x1FFFF);
  }
}

// ---------------- layer-1 mean aggregation: 16 lanes per node -> fp8 mean ----
__launch_bounds__(256)
__global__ void agg_mean1_kernel(const int* __restrict__ rowptr, const int* __restrict__ ebuf,
                                 const uint2* __restrict__ xq2, unsigned char* __restrict__ a8) {
  int t = blockIdx.x * 256 + threadIdx.x;
  int node = t >> 4, q = t & 15;
  bool valid = node < N_NODES;
  int anode = valid ? node : 0;
  int beg = rowptr[anode], end = rowptr[anode + 1];
  if (!valid) end = beg;
  f32x2 acc[4];
#pragma unroll
  for (int i = 0; i < 4; ++i) acc[i] = (f32x2){0.f, 0.f};
  int e = beg;
  for (; e + 4 <= end; e += 4) {
    int s0 = ebuf[e], s1 = ebuf[e + 1], s2 = ebuf[e + 2], s3 = ebuf[e + 3];
    uint2 a = xq2[(unsigned)(s0 * 16 + q)];
    uint2 b = xq2[(unsigned)(s1 * 16 + q)];
    uint2 c = xq2[(unsigned)(s2 * 16 + q)];
    uint2 d = xq2[(unsigned)(s3 * 16 + q)];
    ACC_U32(a.x, 0) ACC_U32(a.y, 2)
    ACC_U32(b.x, 0) ACC_U32(b.y, 2)
    ACC_U32(c.x, 0) ACC_U32(c.y, 2)
    ACC_U32(d.x, 0) ACC_U32(d.y, 2)
  }
  for (; e < end; ++e) {
    int s = ebuf[e];
    uint2 a = xq2[(unsigned)(s * 16 + q)];
    ACC_U32(a.x, 0) ACC_U32(a.y, 2)
  }
  if (!valid) return;
  float inv = (end > beg) ? 1.0f / (float)(end - beg) : 0.0f;
  uint2 o;
  unsigned int u0 = __builtin_amdgcn_cvt_pk_fp8_f32(acc[0][0] * inv, acc[0][1] * inv, 0, false);
  u0 = __builtin_amdgcn_cvt_pk_fp8_f32(acc[1][0] * inv, acc[1][1] * inv, u0, true);
  unsigned int u1 = __builtin_amdgcn_cvt_pk_fp8_f32(acc[2][0] * inv, acc[2][1] * inv, 0, false);
  u1 = __builtin_amdgcn_cvt_pk_fp8_f32(acc[3][0] * inv, acc[3][1] * inv, u1, true);
  o.x = u0; o.y = u1;
  *(uint2*)(a8 + (size_t)node * 256 + q * 8) = o;
}

// ---------------- gemm1 (fp8 MFMA): h8 = fp8(relu(a8@W1bt8^T/16 + b1)) -------
// tile 128 rows x 128 cols (blockIdx.y picks col-half), BK=128 bytes.
__launch_bounds__(256)
__global__ void gemm1_fp8_kernel(const unsigned char* __restrict__ A8,
                                 const unsigned char* __restrict__ B8,
                                 const float* __restrict__ bias,
                                 unsigned char* __restrict__ H8, int M) {
  __shared__ unsigned char ldsA[128 * 128];  // 16 KB
  __shared__ unsigned char ldsB[128 * 128];  // 16 KB
  const int tid = threadIdx.x;
  const int lane = tid & 63;
  const int wm = (tid >> 6) & 1, wn = tid >> 7;
  const int rowBase = blockIdx.x * 128;
  const int colBase = blockIdx.y * 128;
  f32x4 acc[4][4];
#pragma unroll
  for (int i = 0; i < 4; ++i)
#pragma unroll
    for (int j = 0; j < 4; ++j) acc[i][j] = (f32x4){0.f, 0.f, 0.f, 0.f};

  for (int k0 = 0; k0 < 256; k0 += 128) {
#pragma unroll
    for (int i = 0; i < 4; ++i) {
      int s = tid + i * 256;          // 16B slot id: 128 rows x 8 slots
      int row = s >> 3, off16 = s & 7;
      int k16 = off16 ^ (row & 7);    // inverse-swizzled global source
      int ga = rowBase + row; if (ga > M - 1) ga = M - 1;
      gload16(A8 + (size_t)ga * 256 + k0 + k16 * 16, &ldsA[s * 16]);
      gload16(B8 + (size_t)(colBase + row) * 256 + k0 + k16 * 16, &ldsB[s * 16]);
    }
    __syncthreads();
#pragma unroll
    for (int kc = 0; kc < 4; ++kc) {
      long long af[4], bg[4];
#pragma unroll
      for (int i = 0; i < 4; ++i) {
        int rA = wm * 64 + i * 16 + (lane & 15);
        int kb = kc * 32 + (lane >> 4) * 8;           // byte offset of 8 fp8
        int sA = ((kb >> 4) ^ (rA & 7)) * 16 + (kb & 15);
        af[i] = *(const long long*)&ldsA[rA * 128 + sA];
        int rB = wn * 64 + i * 16 + (lane & 15);
        int sB = ((kb >> 4) ^ (rB & 7)) * 16 + (kb & 15);
        bg[i] = *(const long long*)&ldsB[rB * 128 + sB];
      }
#pragma unroll
      for (int mi = 0; mi < 4; ++mi)
#pragma unroll
        for (int ni = 0; ni < 4; ++ni)
          acc[mi][ni] = __builtin_amdgcn_mfma_f32_16x16x32_fp8_fp8(af[mi], bg[ni], acc[mi][ni], 0, 0, 0);
    }
    __syncthreads();
  }
#pragma unroll
  for (int mi = 0; mi < 4; ++mi) {
#pragma unroll
    for (int r = 0; r < 4; ++r) {
      int grow = rowBase + wm * 64 + mi * 16 + (lane >> 4) * 4 + r;
      if (grow >= M) continue;
#pragma unroll
      for (int ni = 0; ni < 4; ++ni) {
        int gcol = colBase + wn * 64 + ni * 16 + (lane & 15);
        float v = fmaxf(acc[mi][ni][r] * 0.0625f + bias[gcol], 0.f);
        H8[(size_t)grow * 256 + gcol] = f2fp8(v);
      }
    }
  }
}

// ---------------- gemm2 (fp8 MFMA): P|Q = (h8 @ W2bt8^T) / 16 ----------------
__launch_bounds__(256)
__global__ void gemm2_fp8_kernel(const unsigned char* __restrict__ A8,
                                 const unsigned char* __restrict__ B8,
                                 unsigned char* __restrict__ P8, ushort_t* __restrict__ QB,
                                 int M) {
  __shared__ unsigned char ldsA[128 * 128];  // 16 KB
  __shared__ unsigned char ldsB[128 * 128];  // 16 KB
  const int tid = threadIdx.x;
  const int lane = tid & 63;
  const int wm = (tid >> 6) & 1, wn = tid >> 7;
  const int rowBase = blockIdx.x * 128;
  f32x4 acc[4][4];
#pragma unroll
  for (int i = 0; i < 4; ++i)
#pragma unroll
    for (int j = 0; j < 4; ++j) acc[i][j] = (f32x4){0.f, 0.f, 0.f, 0.f};

  for (int k0 = 0; k0 < 256; k0 += 128) {
#pragma unroll
    for (int i = 0; i < 4; ++i) {
      int s = tid + i * 256;
      int row = s >> 3, off16 = s & 7;
      int k16 = off16 ^ (row & 7);
      int ga = rowBase + row; if (ga > M - 1) ga = M - 1;
      gload16(A8 + (size_t)ga * 256 + k0 + k16 * 16, &ldsA[s * 16]);
      gload16(B8 + (size_t)row * 256 + k0 + k16 * 16, &ldsB[s * 16]);
    }
    __syncthreads();
#pragma unroll
    for (int kc = 0; kc < 4; ++kc) {
      long long af[4], bg[4];
#pragma unroll
      for (int i = 0; i < 4; ++i) {
        int rA = wm * 64 + i * 16 + (lane & 15);
        int kb = kc * 32 + (lane >> 4) * 8;
        int sA = ((kb >> 4) ^ (rA & 7)) * 16 + (kb & 15);
        af[i] = *(const long long*)&ldsA[rA * 128 + sA];
        int rB = wn * 64 + i * 16 + (lane & 15);
        int sB = ((kb >> 4) ^ (rB & 7)) * 16 + (kb & 15);
        bg[i] = *(const long long*)&ldsB[rB * 128 + sB];
      }
#pragma unroll
      for (int mi = 0; mi < 4; ++mi)
#pragma unroll
        for (int ni = 0; ni < 4; ++ni)
          acc[mi][ni] = __builtin_amdgcn_mfma_f32_16x16x32_fp8_fp8(af[mi], bg[ni], acc[mi][ni], 0, 0, 0);
    }
    __syncthreads();
  }
#pragma unroll
  for (int mi = 0; mi < 4; ++mi) {
#pragma unroll
    for (int r = 0; r < 4; ++r) {
      int grow = rowBase + wm * 64 + mi * 16 + (lane >> 4) * 4 + r;
      if (grow >= M) continue;
#pragma unroll
      for (int ni = 0; ni < 4; ++ni) {
        float v = acc[mi][ni][r] * 0.0625f;
        int c = ni * 16 + (lane & 15);
        if (wn == 0) {
          P8[(size_t)grow * 64 + c] = f2fp8(v);
        } else {
          QB[(size_t)grow * 64 + c] = f2bf(v);
        }
      }
    }
  }
}

// ---------------- final: 4 lanes per node, class-partitioned ----------------
__launch_bounds__(256)
__global__ void final_kernel(const int* __restrict__ rowptr, const int* __restrict__ ebuf,
                             const uint4* __restrict__ p84, const ushort_t* __restrict__ qb,
                             const float* __restrict__ b2, float* __restrict__ out) {
  int t = blockIdx.x * 256 + threadIdx.x;
  int node = t >> 2, q = t & 3;
  bool valid = node < N_NODES;
  int anode = valid ? node : 0;
  int beg = rowptr[anode], end = rowptr[anode + 1];
  if (!valid) end = beg;
  f32x2 acc[8];
#pragma unroll
  for (int i = 0; i < 8; ++i) acc[i] = (f32x2){0.f, 0.f};
  int e = beg;
  for (; e + 4 <= end; e += 4) {
    int s0 = ebuf[e], s1 = ebuf[e + 1], s2 = ebuf[e + 2], s3 = ebuf[e + 3];
    uint4 a = p84[(unsigned)(s0 * 4 + q)];
    uint4 b = p84[(unsigned)(s1 * 4 + q)];
    uint4 c = p84[(unsigned)(s2 * 4 + q)];
    uint4 d = p84[(unsigned)(s3 * 4 + q)];
    ACC_U4(a, 0) ACC_U4(b, 0) ACC_U4(c, 0) ACC_U4(d, 0)
  }
  for (; e < end; ++e) {
    int s = ebuf[e];
    uint4 a = p84[(unsigned)(s * 4 + q)];
    ACC_U4(a, 0)
  }
  float inv = (end > beg) ? 1.0f / (float)(end - beg) : 0.0f;
  f32x2 inv2 = {inv, inv};
#pragma unroll
  for (int i = 0; i < 8; ++i) acc[i] *= inv2;
  const uint4* qrow = (const uint4*)(qb + (size_t)anode * 64 + q * 16);
  const float* bb = b2 + q * 16;
#pragma unroll
  for (int k = 0; k < 2; ++k) {
    uint4 qv = qrow[k];
    acc[4 * k + 0][0] += bb[8 * k + 0] + bf2f(qv.x & 0xffff);
    acc[4 * k + 0][1] += bb[8 * k + 1] + bf2f(qv.x >> 16);
    acc[4 * k + 1][0] += bb[8 * k + 2] + bf2f(qv.y & 0xffff);
    acc[4 * k + 1][1] += bb[8 * k + 3] + bf2f(qv.y >> 16);
    acc[4 * k + 2][0] += bb[8 * k + 4] + bf2f(qv.z & 0xffff);
    acc[4 * k + 2][1] += bb[8 * k + 5] + bf2f(qv.z >> 16);
    acc[4 * k + 3][0] += bb[8 * k + 6] + bf2f(qv.w & 0xffff);
    acc[4 * k + 3][1] += bb[8 * k + 7] + bf2f(qv.w >> 16);
  }
  float mx[8];
#pragma unroll
  for (int i = 0; i < 8; ++i) mx[i] = fmaxf(acc[i][0], acc[i][1]);
#pragma unroll
  for (int s = 4; s >= 1; s >>= 1)
#pragma unroll
    for (int j = 0; j < 4; ++j)
      if (j < s) mx[j] = fmaxf(mx[j], mx[j + s]);
  float m = mx[0];
  m = fmaxf(m, __shfl_xor(m, 1));
  m = fmaxf(m, __shfl_xor(m, 2));
  float sm[8];
#pragma unroll
  for (int i = 0; i < 8; ++i)
    sm[i] = __expf(acc[i][0] - m) + __expf(acc[i][1] - m);
#pragma unroll
  for (int s = 4; s >= 1; s >>= 1)
#pragma unroll
    for (int j = 0; j < 4; ++j)
      if (j < s) sm[j] += sm[j + s];
  float ssum = sm[0];
  ssum += __shfl_xor(ssum, 1);
  ssum += __shfl_xor(ssum, 2);
  if (!valid) return;
  float ls = m + __logf(ssum);
  f32x2 ls2 = {ls, ls};
  float4* orow = (float4*)(out + (size_t)node * 64 + q * 16);
#pragma unroll
  for (int i = 0; i < 4; ++i) {
    f32x2 a = acc[2 * i] - ls2;
    f32x2 b = acc[2 * i + 1] - ls2;
    float4 o = {a[0], a[1], b[0], b[1]};
    orow[i] = o;
  }
}

// ---------------- launch ----------------

extern "C" void kernel_launch(void* const* d_in, const int* in_sizes, int n_in,
                              void* d_out, int out_size, void* d_ws, size_t ws_size,
                              hipStream_t stream) {
  const float* x   = (const float*)d_in[0];
  const int*   ei  = (const int*)d_in[1];
  const float* W1l = (const float*)d_in[2];
  const float* b1  = (const float*)d_in[3];
  const float* W1r = (const float*)d_in[4];
  const float* W2l = (const float*)d_in[5];
  const float* b2  = (const float*)d_in[6];
  const float* W2r = (const float*)d_in[7];
  float* out = (float*)d_out;
  const int* src = ei;
  const int* dst = ei + N_EDGES;

  char* w = (char*)d_ws;
  int*      bucketBase  = (int*)(w);                          // 788 B
  int*      bucketCur   = (int*)(w + 1024);                   // 784 B
  int*      partialHist = (int*)(w + 2048);                   // 100.4 KB
  int*      rowptr      = (int*)(w + 128ull * 1024);          // 400 KB
  int*      ebuf        = (int*)(w + 1024ull * 1024);         // 6.4 MB (ends 7.4)
  unsigned char* W1bt8  = (unsigned char*)(w + 8ull * 1024 * 1024);            // 64 KB
  unsigned char* W2bt8  = (unsigned char*)(w + 8ull * 1024 * 1024 + 128 * 1024);  // 32 KB
  unsigned char* a8     = (unsigned char*)(w + 9ull * 1024 * 1024);    // 25.6 MB (ends 34.6)
  unsigned char* h8     = (unsigned char*)(w + 35ull * 1024 * 1024);   // 25.6 MB (ends 60.6)
  unsigned int* pairs   = (unsigned int*)(w + 61ull * 1024 * 1024);    // 6.4 MB (ends 67.4)
  unsigned int* xq      = (unsigned int*)(w + 68ull * 1024 * 1024);    // 12.8 MB (ends 80.8)
  unsigned int* p8      = (unsigned int*)(w + 81ull * 1024 * 1024);    // 6.4 MB (ends 87.4)
  ushort_t*     qb      = (ushort_t*)(w + 88ull * 1024 * 1024);        // 12.8 MB (ends 100.8)

  const int CVT_BLOCKS = (CVT_TOTAL + 255) / 256;
  count_cvt_kernel<<<NBIN + CVT_BLOCKS, 256, 0, stream>>>(
      dst, partialHist, x, W1l, W1r, W2l, W2r, a8, xq, W1bt8, W2bt8);
  scan_buckets_kernel<<<1, 256, 0, stream>>>(partialHist, bucketBase, bucketCur, rowptr);
  bin_scatter_kernel<<<NBIN, 256, 0, stream>>>(src, dst, bucketCur, pairs);
  bucket_csr_kernel<<<NBKT, 256, 0, stream>>>(pairs, bucketBase, rowptr, ebuf);

  agg_mean1_kernel<<<(16 * N_NODES + 255) / 256, 256, 0, stream>>>(
      rowptr, ebuf, (const uint2*)xq, a8);

  gemm1_fp8_kernel<<<dim3((N_NODES + 127) / 128, 2), 256, 0, stream>>>(
      a8, W1bt8, b1, h8, N_NODES);
  gemm2_fp8_kernel<<<(N_NODES + 127) / 128, 256, 0, stream>>>(
      h8, W2bt8, (unsigned char*)p8, qb, N_NODES);

  final_kernel<<<(4 * N_NODES + 255) / 256, 256, 0, stream>>>(
      rowptr, ebuf, (const uint4*)p8, qb, b2, out);
}